// Round 3
// baseline (1646.992 us; speedup 1.0000x reference)
//
#include <hip/hip_runtime.h>

// CTC loss forward, sum over batch — single producer/consumer kernel.
//
// Budget (rocprof rounds 0-2): two structural 512 MB ws poison fills ~148 us
// cannot be avoided; our stage (~15-25 us, BW-bound gather) + serial
// recurrence (~8 us) + memset + 3 dispatch gaps sum to ~87 us. This round
// overlaps the recurrence UNDER the staging and cuts one dispatch:
//   - grid = 32 consumer blocks + 8000 producer blocks, 256 thr each
//   - producers: wave stages one (t,b) emission row (gather ~102 of 1000
//     cols, exponentiate with +OFF, fp32x4 store), then __threadfence +
//     agent-scope release atomicAdd on chunkflag[b][t/128]
//   - consumers (1 wave, b = blockIdx.x): spin-acquire chunk c, run the
//     recurrence over its rows with a per-chunk PFD=16 register ring;
//     exact pow2 rescale after every step s with s%16==0 (cadence identical
//     to the verified round-2 kernel; pow2 scaling is lossless)
//   - per-b losses -> ws slots; consumer 0 waits a done-counter and writes
//     the deterministic ordered sum to out (no out-memset dispatch needed)
// Deadlock-free under any dispatch order: producers never wait; 32 spinning
// consumer blocks cannot starve 256 CUs; consumer 0 waits only on blocks
// that need no co-residency.

constexpr int T = 1000, B = 32, C = 1000, S = 100;
constexpr int L = 2 * S + 1;            // 201
constexpr int RS = 204;                 // row stride (floats), 16B-aligned rows
constexpr int CH = 128;                 // rows per chunk
constexpr int NCH = (T + CH - 1) / CH;  // 8
constexpr int PFD = 16;                 // per-chunk prefetch ring depth
constexpr float OFF = 7.0f;             // emission log-offset
constexpr float LOG2E = 1.4426950408889634f;
constexpr float LN2 = 0.6931471805599453f;

constexpr size_t DATA_WORDS = (size_t)B * T * RS;  // 6,528,000 floats
constexpr int FLAG_WORDS = B * NCH;                // 256
constexpr int CTRL_WORDS = FLAG_WORDS + 1 + B;     // flags, done, loss[B]

// DPP wave_shr:1 — lane i reads lane i-1; lane 0 gets 0 (bound_ctrl).
__device__ __forceinline__ float dpp_shr1(float x) {
    return __int_as_float(
        __builtin_amdgcn_update_dpp(0, __float_as_int(x), 0x138, 0xF, 0xF, true));
}

// Wave-wide max of NONNEGATIVE values via gfx9 DPP ladder; result uniform.
__device__ __forceinline__ float wave_max_nonneg(float x) {
#define DPP_MAX(ctrl)                                                        \
    x = fmaxf(x, __int_as_float(__builtin_amdgcn_update_dpp(                 \
                     0, __float_as_int(x), (ctrl), 0xF, 0xF, true)))
    DPP_MAX(0x111);  // row_shr:1
    DPP_MAX(0x112);  // row_shr:2
    DPP_MAX(0x114);  // row_shr:4
    DPP_MAX(0x118);  // row_shr:8
    DPP_MAX(0x142);  // row_bcast15
    DPP_MAX(0x143);  // row_bcast31 -> lane63 holds wave max
#undef DPP_MAX
    return __int_as_float(__builtin_amdgcn_readlane(__float_as_int(x), 63));
}

__global__ void __launch_bounds__(256, 1) ctc_pc_kernel(
        const float* __restrict__ logp, const int* __restrict__ targets,
        const int* __restrict__ input_lens, const int* __restrict__ target_lens,
        float* __restrict__ ws, float* __restrict__ out) {
    const int lane = threadIdx.x & 63;
    const int wv = threadIdx.x >> 6;
    int* ctrl = (int*)(ws + DATA_WORDS);
    int* flags = ctrl;                         // [B][NCH] row counters
    int* done = ctrl + FLAG_WORDS;             // finished-consumer counter
    float* loss_slot = (float*)(ctrl + FLAG_WORDS + 1);  // [B]

    if (blockIdx.x >= (unsigned)B) {
        // ---------------- producer: one (t,b) row per wave ----------------
        const int r = (blockIdx.x - B) * 4 + wv;  // 0..31999
        const int t = r >> 5;                     // t-major: chunk 0 first
        const int b = r & 31;
        if (t < T) {
            if (lane <= 50) {
                const int col = 4 * lane;
                const float* row = logp + ((size_t)t * B + b) * C;
                const float pb = exp2f((row[0] + OFF) * LOG2E);
                float p1 = 0.f, p3 = 0.f;
                const int l1 = col + 1;
                if (l1 < L)
                    p1 = exp2f((row[targets[b * S + (l1 >> 1)]] + OFF) * LOG2E);
                const int l3 = col + 3;
                if (l3 < L)
                    p3 = exp2f((row[targets[b * S + (l3 >> 1)]] + OFF) * LOG2E);
                float4 v;
                v.x = pb;                        // even col, always < L
                v.y = p1;                        // 0 for lane-50 pad
                v.z = (col + 2 < L) ? pb : 0.f;  // 0 for lane-50 pad
                v.w = p3;                        // 0 for lane-50 pad
                *reinterpret_cast<float4*>(ws + ((size_t)b * T + t) * RS + col) = v;
            }
            __threadfence();  // wave-level vm drain + device-scope visibility
            if (lane == 0)
                __hip_atomic_fetch_add(&flags[b * NCH + (t >> 7)], 1,
                                       __ATOMIC_RELEASE, __HIP_MEMORY_SCOPE_AGENT);
        }
        return;
    }

    // ---------------- consumer: one wave per batch element ----------------
    if (wv != 0) return;
    const int b = blockIdx.x;
    const int Tb = min(input_lens[b], T);
    const int tl = target_lens[b];
    const float* pw = ws + (size_t)b * T * RS;
    // lanes 0..50 own positions 4*lane..4*lane+3; lanes 51..63 dead (clamped)
    const int col = (lane <= 50) ? 4 * lane : 200;

    // Skip masks: only odd positions (col+1, col+3) can skip.
    float m1 = 0.f, m3 = 0.f;
    if (lane <= 50) {
        const int l1 = col + 1;
        if (l1 >= 3 && l1 < L) {
            const int s = (l1 - 1) >> 1;
            if (targets[b * S + s] != targets[b * S + s - 1]) m1 = 1.f;
        }
        const int l3 = col + 3;
        if (l3 >= 3 && l3 < L) {
            const int s = (l3 - 1) >> 1;
            if (targets[b * S + s] != targets[b * S + s - 1]) m3 = 1.f;
        }
    }

    auto wait_chunk = [&](int c) {
        const int expect = (c + 1) * CH <= T ? CH : T - c * CH;
        if (lane == 0) {
            while (__hip_atomic_load(&flags[b * NCH + c], __ATOMIC_ACQUIRE,
                                     __HIP_MEMORY_SCOPE_AGENT) < expect)
                __builtin_amdgcn_s_sleep(4);
        }
        __threadfence();  // wave-wide: subsequent loads see released data
    };

    wait_chunk(0);

    // init at t=0: alpha[0] = p(blank), alpha[1] = p(tgt0), rest 0
    float a0 = 0.f, a1 = 0.f, a2 = 0.f, a3 = 0.f;
    {
        const float4 q0 = *reinterpret_cast<const float4*>(pw + col);
        if (lane == 0) { a0 = q0.x; a1 = q0.y; }
    }
    int esum = 0;

    // Dead-lane invariant: lane 50's cols 201..203 staged 0 -> its a1..a3
    // stay 0; lanes 51+ start 0 and only ever receive lane 50's zero a3.
#define CTC_STEP(Q_)                                  \
    do {                                              \
        const float am1 = dpp_shr1(a3);               \
        const float s01 = a0 + a1;                    \
        const float s23 = a2 + a3;                    \
        const float n0 = (a0 + am1) * (Q_).x;         \
        const float n1 = fmaf(am1, m1, s01) * (Q_).y; \
        const float n2 = (a1 + a2) * (Q_).z;          \
        const float n3 = fmaf(a1, m3, s23) * (Q_).w;  \
        a0 = n0; a1 = n1; a2 = n2; a3 = n3;           \
    } while (0)

#define CTC_RESCALE()                                                          \
    do {                                                                       \
        const float mx = wave_max_nonneg(fmaxf(fmaxf(a0, a1), fmaxf(a2, a3))); \
        const unsigned bits = __float_as_uint(mx);                             \
        if (bits != 0u) {                                                      \
            const int e = (int)((bits >> 23) & 0xFFu) - 127;                   \
            const float sc = __uint_as_float((unsigned)(127 - e) << 23);       \
            a0 *= sc; a1 *= sc; a2 *= sc; a3 *= sc;                            \
            esum += e;                                                         \
        }                                                                      \
    } while (0)

    // process steps [ts, te) out of the current (acquired) chunk
    auto process_range = [&](int ts, int te) {
        float4 P[PFD];
        int tp = ts;  // next row to (pre)fetch; never crosses te
#pragma unroll
        for (int i = 0; i < PFD; ++i) {
            if (tp < te)
                P[i] = *reinterpret_cast<const float4*>(pw + (size_t)tp * RS + col);
            ++tp;
        }
        int tt = ts;
        while (tt + PFD <= te) {
#pragma unroll
            for (int i = 0; i < PFD; ++i) {
                const float4 q = P[i];
                if (tp < te)
                    P[i] = *reinterpret_cast<const float4*>(pw + (size_t)tp * RS + col);
                ++tp;
                CTC_STEP(q);
                if (((tt + i) & 15) == 0) CTC_RESCALE();  // step s = tt+i
            }
            tt += PFD;
        }
        const int rem = te - tt;
#pragma unroll
        for (int i = 0; i < PFD; ++i) {
            if (i < rem) {
                const float4 q = P[i];
                CTC_STEP(q);
                if (((tt + i) & 15) == 0) CTC_RESCALE();
            }
        }
    };

    int t = 1, c = 0;
    while (t < Tb) {
        const int te = min((c + 1) * CH, Tb);
        if (c > 0) wait_chunk(c);
        process_range(t, te);
        t = te;
        ++c;
    }
#undef CTC_STEP
#undef CTC_RESCALE

    // final: sum alpha at positions 2*tl and 2*tl-1
    const int e1 = 2 * tl, e2 = 2 * tl - 1;
    float contrib = 0.f;
    if (lane <= 50) {
        if (col + 0 == e1 || col + 0 == e2) contrib += a0;
        if (col + 1 == e1 || col + 1 == e2) contrib += a1;
        if (col + 2 == e1 || col + 2 == e2) contrib += a2;
        if (col + 3 == e1 || col + 3 == e2) contrib += a3;
    }
#pragma unroll
    for (int off = 32; off; off >>= 1) contrib += __shfl_xor(contrib, off);

    if (lane == 0) {
        const float logalpha = logf(contrib) + (float)esum * LN2 - OFF * (float)Tb;
        float loss = -logalpha;
        if (!(loss < 0.5e30f)) loss = 0.f;  // zero_infinity (catches NaN/inf)
        loss_slot[b] = loss;
    }
    __threadfence();
    if (lane == 0)
        __hip_atomic_fetch_add(done, 1, __ATOMIC_RELEASE, __HIP_MEMORY_SCOPE_AGENT);

    if (b == 0) {
        if (lane == 0) {
            while (__hip_atomic_load(done, __ATOMIC_ACQUIRE,
                                     __HIP_MEMORY_SCOPE_AGENT) < B)
                __builtin_amdgcn_s_sleep(8);
        }
        __threadfence();
        if (lane == 0) {
            float s = 0.f;
            for (int i = 0; i < B; ++i) s += loss_slot[i];
            out[0] = s;  // deterministic ordered sum; no out-memset needed
        }
    }
}

// ---------------- Fallback: direct gather (if ws too small) ----------------
__global__ void __launch_bounds__(64, 1) ctc_direct_kernel(
        const float* __restrict__ logp, const int* __restrict__ targets,
        const int* __restrict__ input_lens, const int* __restrict__ target_lens,
        float* __restrict__ out) {
    const int b = blockIdx.x;
    const int lane = threadIdx.x;
    const int col = (lane <= 50) ? 4 * lane : 200;
    const int Tb = input_lens[b];
    const int tl = target_lens[b];

    int cc[4]; float mm[4], pm[4];
#pragma unroll
    for (int i = 0; i < 4; ++i) {
        const int l = col + i;
        const bool real = (lane <= 50) && (l < L);
        pm[i] = real ? 1.f : 0.f;
        cc[i] = real ? ((l & 1) ? targets[b * S + (l >> 1)] : 0) : 0;
        float mk = 0.f;
        if (real && (l & 1) && l >= 3) {
            const int s = (l - 1) >> 1;
            if (targets[b * S + s] != targets[b * S + s - 1]) mk = 1.f;
        }
        mm[i] = mk;
    }
    const float m1 = mm[1], m3 = mm[3];

    float a0 = 0.f, a1 = 0.f, a2 = 0.f, a3 = 0.f;
    {
        const float* rowp = logp + (size_t)b * C;
        const float p0 = pm[0] * exp2f((rowp[cc[0]] + OFF) * LOG2E);
        const float p1 = pm[1] * exp2f((rowp[cc[1]] + OFF) * LOG2E);
        if (lane == 0) { a0 = p0; a1 = p1; }
    }
    int esum = 0;

    for (int t = 1; t < Tb; ++t) {
        const float* rowp = logp + ((size_t)t * B + b) * C;
        const float p0 = pm[0] * exp2f((rowp[cc[0]] + OFF) * LOG2E);
        const float p1 = pm[1] * exp2f((rowp[cc[1]] + OFF) * LOG2E);
        const float p2 = pm[2] * exp2f((rowp[cc[2]] + OFF) * LOG2E);
        const float p3 = pm[3] * exp2f((rowp[cc[3]] + OFF) * LOG2E);
        const float am1 = dpp_shr1(a3);
        const float n0 = (a0 + am1) * p0;
        const float n1 = fmaf(am1, m1, a0 + a1) * p1;
        const float n2 = (a1 + a2) * p2;
        const float n3 = fmaf(a1, m3, a2 + a3) * p3;
        a0 = n0; a1 = n1; a2 = n2; a3 = n3;
        if ((t & 15) == 0) {
            const float mx = wave_max_nonneg(fmaxf(fmaxf(a0, a1), fmaxf(a2, a3)));
            const unsigned bits = __float_as_uint(mx);
            if (bits != 0u) {
                const int e = (int)((bits >> 23) & 0xFFu) - 127;
                const float sc = __uint_as_float((unsigned)(127 - e) << 23);
                a0 *= sc; a1 *= sc; a2 *= sc; a3 *= sc;
                esum += e;
            }
        }
    }

    const int e1 = 2 * tl, e2 = 2 * tl - 1;
    float contrib = 0.f;
    if (lane <= 50) {
        if (col + 0 == e1 || col + 0 == e2) contrib += a0;
        if (col + 1 == e1 || col + 1 == e2) contrib += a1;
        if (col + 2 == e1 || col + 2 == e2) contrib += a2;
        if (col + 3 == e1 || col + 3 == e2) contrib += a3;
    }
#pragma unroll
    for (int off = 32; off; off >>= 1) contrib += __shfl_xor(contrib, off);
    if (lane == 0) {
        const float logalpha = logf(contrib) + (float)esum * LN2 - OFF * (float)Tb;
        float loss = -logalpha;
        if (!(loss < 0.5e30f)) loss = 0.f;
        atomicAdd(out, loss);
    }
}

extern "C" void kernel_launch(void* const* d_in, const int* in_sizes, int n_in,
                              void* d_out, int out_size, void* d_ws, size_t ws_size,
                              hipStream_t stream) {
    (void)in_sizes; (void)n_in; (void)out_size;
    const float* logp = (const float*)d_in[0];
    const int* targets = (const int*)d_in[1];
    const int* input_lens = (const int*)d_in[2];
    const int* target_lens = (const int*)d_in[3];
    float* out = (float*)d_out;
    float* ws = (float*)d_ws;

    const size_t ws_needed = (DATA_WORDS + (size_t)CTRL_WORDS) * sizeof(float);
    if (ws_size >= ws_needed) {
        // zero the 1.2 KB control block (flags/done/loss) — data needs no init
        hipMemsetAsync(ws + DATA_WORDS, 0, CTRL_WORDS * sizeof(float), stream);
        const int nprod = (B * T) / 4;  // 8000 producer blocks (4 rows each)
        ctc_pc_kernel<<<B + nprod, 256, 0, stream>>>(logp, targets, input_lens,
                                                     target_lens, ws, out);
    } else {
        hipMemsetAsync(d_out, 0, sizeof(float), stream);
        ctc_direct_kernel<<<B, 64, 0, stream>>>(logp, targets, input_lens,
                                                target_lens, out);
    }
}

// Round 4
// 308.147 us; speedup vs baseline: 5.3448x; 5.3448x over previous
//
#include <hip/hip_runtime.h>
#include <hip/hip_cooperative_groups.h>

// CTC loss forward, sum over batch — single COOPERATIVE kernel.
//
// Round-3 lesson (rocprof): per-row __threadfence + agent-scope atomics
// (32000 of them) serialize the chip via L2 writeback storms -> 65 GB/s,
// 1583 us. Cross-block sync must happen O(1) times. This round uses the
// harness-sanctioned grid barrier instead:
//   - hipLaunchCooperativeKernel, 256 blocks x 256 thr (1 block/CU)
//   - phase 1: all 1024 waves stage emissions (32 waves per b, ~32 rows
//     each; scattered loads BATCHED 4 rows deep for memory-level
//     parallelism; targets hoisted to registers)
//   - grid.sync()
//   - phase 2: wave 0 of blocks 0..31 runs the serial alpha recurrence
//     (identical numerics to the verified round-2 kernel: fp32 ring
//     PFD=32, exact pow2 rescale at steps t%16==0)
//   - grid.sync(); block 0 writes the deterministic ordered sum to out
// One dispatch, no out-memset. Host falls back to the proven round-2
// two-kernel path if the cooperative launch is rejected.

namespace cg = cooperative_groups;

constexpr int T = 1000, B = 32, C = 1000, S = 100;
constexpr int L = 2 * S + 1;      // 201
constexpr int RS = 204;           // row stride (floats) = 816 B, 16B-aligned
constexpr int PFD = 32;           // prefetch ring depth (recurrence)
constexpr int RROWS = T + PFD;    // pad rows so the ring prefetch stays in-bounds
constexpr float OFF = 7.0f;       // emission log-offset
constexpr float LOG2E = 1.4426950408889634f;
constexpr float LN2 = 0.6931471805599453f;

constexpr int GBLK = 256;                    // cooperative grid blocks
constexpr int WPB = 4;                       // waves per block (256 thr)
constexpr int NW = GBLK * WPB;               // 1024 staging waves
constexpr int WAVES_PER_B = NW / B;          // 32
constexpr int TSEG = (T + WAVES_PER_B - 1) / WAVES_PER_B;  // 32 rows per wave
static_assert(NW % B == 0, "wave mapping");

constexpr size_t DATA_WORDS = (size_t)B * RROWS * RS;  // ~26.9 MB of floats

// DPP wave_shr:1 — lane i reads lane i-1; lane 0 gets 0 (bound_ctrl).
__device__ __forceinline__ float dpp_shr1(float x) {
    return __int_as_float(
        __builtin_amdgcn_update_dpp(0, __float_as_int(x), 0x138, 0xF, 0xF, true));
}

// Wave-wide max of NONNEGATIVE values via gfx9 DPP ladder; result uniform.
__device__ __forceinline__ float wave_max_nonneg(float x) {
#define DPP_MAX(ctrl)                                                        \
    x = fmaxf(x, __int_as_float(__builtin_amdgcn_update_dpp(                 \
                     0, __float_as_int(x), (ctrl), 0xF, 0xF, true)))
    DPP_MAX(0x111);  // row_shr:1
    DPP_MAX(0x112);  // row_shr:2
    DPP_MAX(0x114);  // row_shr:4
    DPP_MAX(0x118);  // row_shr:8
    DPP_MAX(0x142);  // row_bcast15
    DPP_MAX(0x143);  // row_bcast31 -> lane63 holds wave max
#undef DPP_MAX
    return __int_as_float(__builtin_amdgcn_readlane(__float_as_int(x), 63));
}

// ---- shared recurrence body (identical numerics to verified round-2) ----
// Returns the per-sequence loss (uniform across the wave).
__device__ float ctc_wave_loss(const float* __restrict__ pw,
                               const int* __restrict__ targets, int b, int Tb,
                               int tl, int lane) {
    // lanes 0..50 own positions 4*lane..4*lane+3; lanes 51..63 dead (clamped)
    const int col = (lane <= 50) ? 4 * lane : 200;

    // Skip masks: only odd positions (col+1, col+3) can skip.
    float m1 = 0.f, m3 = 0.f;
    if (lane <= 50) {
        const int l1 = col + 1;
        if (l1 >= 3 && l1 < L) {
            const int s = (l1 - 1) >> 1;
            if (targets[b * S + s] != targets[b * S + s - 1]) m1 = 1.f;
        }
        const int l3 = col + 3;
        if (l3 >= 3 && l3 < L) {
            const int s = (l3 - 1) >> 1;
            if (targets[b * S + s] != targets[b * S + s - 1]) m3 = 1.f;
        }
    }

    // init at t=0: alpha[0] = p(blank), alpha[1] = p(tgt0), rest 0
    float a0 = 0.f, a1 = 0.f, a2 = 0.f, a3 = 0.f;
    {
        const float4 q0 = *reinterpret_cast<const float4*>(pw + col);
        if (lane == 0) { a0 = q0.x; a1 = q0.y; }
    }
    int esum = 0;

    // Dead-lane invariant: lane 50's cols 201..203 staged 0 -> its a1..a3
    // stay 0; lanes 51+ start 0 and only ever receive lane 50's zero a3.
#define CTC_STEP(Q_)                                  \
    do {                                              \
        const float am1 = dpp_shr1(a3);               \
        const float s01 = a0 + a1;                    \
        const float s23 = a2 + a3;                    \
        const float n0 = (a0 + am1) * (Q_).x;         \
        const float n1 = fmaf(am1, m1, s01) * (Q_).y; \
        const float n2 = (a1 + a2) * (Q_).z;          \
        const float n3 = fmaf(a1, m3, s23) * (Q_).w;  \
        a0 = n0; a1 = n1; a2 = n2; a3 = n3;           \
    } while (0)

#define CTC_RESCALE()                                                          \
    do {                                                                       \
        const float mx = wave_max_nonneg(fmaxf(fmaxf(a0, a1), fmaxf(a2, a3))); \
        const unsigned bits = __float_as_uint(mx);                             \
        if (bits != 0u) {                                                      \
            const int e = (int)((bits >> 23) & 0xFFu) - 127;                   \
            const float sc = __uint_as_float((unsigned)(127 - e) << 23);       \
            a0 *= sc; a1 *= sc; a2 *= sc; a3 *= sc;                            \
            esum += e;                                                         \
        }                                                                      \
    } while (0)

    // prefetch ring: P[i] holds the emission row (float4) for step t+i
    float4 P[PFD];
    {
        const float* pf0 = pw + (size_t)RS + col;
#pragma unroll
        for (int i = 0; i < PFD; ++i)
            P[i] = *reinterpret_cast<const float4*>(pf0 + (size_t)i * RS);
    }
    const float* pf = pw + (size_t)(PFD + 1) * RS + col;  // next row to fetch

    int t = 1;
    while (t + PFD <= Tb) {
#pragma unroll
        for (int i = 0; i < PFD; ++i) {
            const float4 q = P[i];
            P[i] = *reinterpret_cast<const float4*>(pf);  // PFD steps ahead
            pf += RS;
            CTC_STEP(q);
            if (i == 15) CTC_RESCALE();  // 16-step rescale cadence
        }
        CTC_RESCALE();
        t += PFD;
    }
    // tail (< PFD steps)
    {
        const int rem = Tb - t;
#pragma unroll
        for (int i = 0; i < PFD; ++i) {
            if (i < rem) {
                const float4 q = P[i];
                CTC_STEP(q);
                if (i == 15) CTC_RESCALE();  // bound any unrescaled run
            }
        }
    }
#undef CTC_STEP
#undef CTC_RESCALE

    // final: sum alpha at positions 2*tl and 2*tl-1
    const int e1 = 2 * tl, e2 = 2 * tl - 1;
    float contrib = 0.f;
    if (lane <= 50) {
        if (col + 0 == e1 || col + 0 == e2) contrib += a0;
        if (col + 1 == e1 || col + 1 == e2) contrib += a1;
        if (col + 2 == e1 || col + 2 == e2) contrib += a2;
        if (col + 3 == e1 || col + 3 == e2) contrib += a3;
    }
#pragma unroll
    for (int off = 32; off; off >>= 1) contrib += __shfl_xor(contrib, off);

    const float logalpha = logf(contrib) + (float)esum * LN2 - OFF * (float)Tb;
    float loss = -logalpha;
    if (!(loss < 0.5e30f)) loss = 0.f;  // zero_infinity (catches NaN/inf)
    return loss;
}

// ---------------- cooperative fused kernel ----------------
__global__ void __launch_bounds__(256, 1) ctc_coop_kernel(
        const float* __restrict__ logp, const int* __restrict__ targets,
        const int* __restrict__ input_lens, const int* __restrict__ target_lens,
        float* __restrict__ ws, float* __restrict__ out) {
    const int lane = threadIdx.x & 63;
    const int wv = threadIdx.x >> 6;
    float* loss_slot = ws + DATA_WORDS;  // [B]

    // ---------------- phase 1: stage emissions ----------------
    {
        const int gw = blockIdx.x * WPB + wv;   // 0..1023
        const int b = gw / WAVES_PER_B;         // 0..31
        const int seg = gw % WAVES_PER_B;       // 0..31
        const int t0 = seg * TSEG;
        const int t1 = min(t0 + TSEG, T);
        const int col = 4 * lane;
        const bool ln = (lane <= 50);
        const bool h1 = ln && (col + 1 < L);    // lane <= 49
        const bool h3 = ln && (col + 3 < L);    // lane <= 49
        const int c1 = h1 ? targets[b * S + 2 * lane] : 0;
        const int c3 = h3 ? targets[b * S + 2 * lane + 1] : 0;
        float* wb = ws + (size_t)b * RROWS * RS;

        for (int t = t0; t < t1; t += 4) {
            const int n = min(4, t1 - t);  // wave-uniform
            float f0[4], fa[4], fb[4];
            // gather phase: up to 12 independent scattered loads in flight
#pragma unroll
            for (int j = 0; j < 4; ++j) {
                if (j < n) {
                    const float* row = logp + ((size_t)(t + j) * B + b) * C;
                    f0[j] = row[0];
                    fa[j] = h1 ? row[c1] : 0.f;
                    fb[j] = h3 ? row[c3] : 0.f;
                }
            }
            // compute + store phase
#pragma unroll
            for (int j = 0; j < 4; ++j) {
                if (j < n && ln) {
                    const float pb = exp2f((f0[j] + OFF) * LOG2E);
                    const float p1 = h1 ? exp2f((fa[j] + OFF) * LOG2E) : 0.f;
                    const float p3 = h3 ? exp2f((fb[j] + OFF) * LOG2E) : 0.f;
                    float4 v;
                    v.x = pb;                        // even col, always < L
                    v.y = p1;                        // 0 on lane-50 pad
                    v.z = (col + 2 < L) ? pb : 0.f;  // 0 on lane-50 pad
                    v.w = p3;                        // 0 on lane-50 pad
                    *reinterpret_cast<float4*>(wb + (size_t)(t + j) * RS + col) = v;
                }
            }
        }
    }

    cg::this_grid().sync();

    // ---------------- phase 2: recurrence (32 waves total) ----------------
    if (blockIdx.x < (unsigned)B && wv == 0) {
        const int b = blockIdx.x;
        const int Tb = min(input_lens[b], T);
        const int tl = target_lens[b];
        const float* pw = ws + (size_t)b * RROWS * RS;
        const float loss = ctc_wave_loss(pw, targets, b, Tb, tl, lane);
        if (lane == 0) loss_slot[b] = loss;
    }

    cg::this_grid().sync();

    // ---------------- phase 3: deterministic ordered sum ----------------
    if (blockIdx.x == 0 && threadIdx.x == 0) {
        float s = 0.f;
        for (int i = 0; i < B; ++i) s += loss_slot[i];
        out[0] = s;  // full overwrite — no out-memset dispatch needed
    }
}

// ---------------- fallback path A: round-2 two-kernel (proven) ----------------
__global__ void __launch_bounds__(256) stage_kernel(
        const float* __restrict__ logp, const int* __restrict__ targets,
        float* __restrict__ ws) {
    const int t = blockIdx.x * 4 + (threadIdx.x >> 6);
    const int b = blockIdx.y;
    const int lane = threadIdx.x & 63;
    if (lane > 50) return;
    const int col = 4 * lane;
    const float* row = logp + ((size_t)t * B + b) * C;

    const float pb = exp2f((row[0] + OFF) * LOG2E);
    float p1 = 0.f, p3 = 0.f;
    const int l1 = col + 1;
    if (l1 < L) p1 = exp2f((row[targets[b * S + (l1 >> 1)]] + OFF) * LOG2E);
    const int l3 = col + 3;
    if (l3 < L) p3 = exp2f((row[targets[b * S + (l3 >> 1)]] + OFF) * LOG2E);

    float4 v;
    v.x = pb;
    v.y = p1;
    v.z = (col + 2 < L) ? pb : 0.f;
    v.w = p3;
    *reinterpret_cast<float4*>(ws + ((size_t)b * RROWS + t) * RS + col) = v;
}

__global__ void __launch_bounds__(64, 1) ctc_kernel(
        const float* __restrict__ ws, const int* __restrict__ targets,
        const int* __restrict__ input_lens, const int* __restrict__ target_lens,
        float* __restrict__ out) {
    const int b = blockIdx.x;
    const int lane = threadIdx.x;
    const int Tb = input_lens[b];
    const int tl = target_lens[b];
    const float* pw = ws + (size_t)b * RROWS * RS;
    const float loss = ctc_wave_loss(pw, targets, b, Tb, tl, lane);
    if (lane == 0) atomicAdd(out, loss);
}

// ---------------- fallback path B: direct gather (ws too small) ----------------
__global__ void __launch_bounds__(64, 1) ctc_direct_kernel(
        const float* __restrict__ logp, const int* __restrict__ targets,
        const int* __restrict__ input_lens, const int* __restrict__ target_lens,
        float* __restrict__ out) {
    const int b = blockIdx.x;
    const int lane = threadIdx.x;
    const int col = (lane <= 50) ? 4 * lane : 200;
    const int Tb = input_lens[b];
    const int tl = target_lens[b];

    int cc[4]; float mm[4], pm[4];
#pragma unroll
    for (int i = 0; i < 4; ++i) {
        const int l = col + i;
        const bool real = (lane <= 50) && (l < L);
        pm[i] = real ? 1.f : 0.f;
        cc[i] = real ? ((l & 1) ? targets[b * S + (l >> 1)] : 0) : 0;
        float mk = 0.f;
        if (real && (l & 1) && l >= 3) {
            const int s = (l - 1) >> 1;
            if (targets[b * S + s] != targets[b * S + s - 1]) mk = 1.f;
        }
        mm[i] = mk;
    }
    const float m1 = mm[1], m3 = mm[3];

    float a0 = 0.f, a1 = 0.f, a2 = 0.f, a3 = 0.f;
    {
        const float* rowp = logp + (size_t)b * C;
        const float p0 = pm[0] * exp2f((rowp[cc[0]] + OFF) * LOG2E);
        const float p1 = pm[1] * exp2f((rowp[cc[1]] + OFF) * LOG2E);
        if (lane == 0) { a0 = p0; a1 = p1; }
    }
    int esum = 0;

    for (int t = 1; t < Tb; ++t) {
        const float* rowp = logp + ((size_t)t * B + b) * C;
        const float p0 = pm[0] * exp2f((rowp[cc[0]] + OFF) * LOG2E);
        const float p1 = pm[1] * exp2f((rowp[cc[1]] + OFF) * LOG2E);
        const float p2 = pm[2] * exp2f((rowp[cc[2]] + OFF) * LOG2E);
        const float p3 = pm[3] * exp2f((rowp[cc[3]] + OFF) * LOG2E);
        const float am1 = dpp_shr1(a3);
        const float n0 = (a0 + am1) * p0;
        const float n1 = fmaf(am1, m1, a0 + a1) * p1;
        const float n2 = (a1 + a2) * p2;
        const float n3 = fmaf(a1, m3, a2 + a3) * p3;
        a0 = n0; a1 = n1; a2 = n2; a3 = n3;
        if ((t & 15) == 0) {
            const float mx = wave_max_nonneg(fmaxf(fmaxf(a0, a1), fmaxf(a2, a3)));
            const unsigned bits = __float_as_uint(mx);
            if (bits != 0u) {
                const int e = (int)((bits >> 23) & 0xFFu) - 127;
                const float sc = __uint_as_float((unsigned)(127 - e) << 23);
                a0 *= sc; a1 *= sc; a2 *= sc; a3 *= sc;
                esum += e;
            }
        }
    }

    const int e1 = 2 * tl, e2 = 2 * tl - 1;
    float contrib = 0.f;
    if (lane <= 50) {
        if (col + 0 == e1 || col + 0 == e2) contrib += a0;
        if (col + 1 == e1 || col + 1 == e2) contrib += a1;
        if (col + 2 == e1 || col + 2 == e2) contrib += a2;
        if (col + 3 == e1 || col + 3 == e2) contrib += a3;
    }
#pragma unroll
    for (int off = 32; off; off >>= 1) contrib += __shfl_xor(contrib, off);
    if (lane == 0) {
        const float logalpha = logf(contrib) + (float)esum * LN2 - OFF * (float)Tb;
        float loss = -logalpha;
        if (!(loss < 0.5e30f)) loss = 0.f;
        atomicAdd(out, loss);
    }
}

extern "C" void kernel_launch(void* const* d_in, const int* in_sizes, int n_in,
                              void* d_out, int out_size, void* d_ws, size_t ws_size,
                              hipStream_t stream) {
    (void)in_sizes; (void)n_in; (void)out_size;
    const float* logp = (const float*)d_in[0];
    const int* targets = (const int*)d_in[1];
    const int* input_lens = (const int*)d_in[2];
    const int* target_lens = (const int*)d_in[3];
    float* out = (float*)d_out;
    float* ws = (float*)d_ws;

    const size_t ws_needed = (DATA_WORDS + (size_t)B) * sizeof(float);
    if (ws_size >= ws_needed) {
        void* args[] = {(void*)&logp, (void*)&targets, (void*)&input_lens,
                        (void*)&target_lens, (void*)&ws, (void*)&out};
        const hipError_t err = hipLaunchCooperativeKernel(
            (const void*)ctc_coop_kernel, dim3(GBLK), dim3(256), args, 0, stream);
        if (err == hipSuccess) return;
        // cooperative launch rejected -> proven round-2 two-kernel path
        hipMemsetAsync(d_out, 0, sizeof(float), stream);
        dim3 gA(T / 4, B);
        stage_kernel<<<gA, 256, 0, stream>>>(logp, targets, ws);
        ctc_kernel<<<B, 64, 0, stream>>>(ws, targets, input_lens, target_lens, out);
    } else {
        hipMemsetAsync(d_out, 0, sizeof(float), stream);
        ctc_direct_kernel<<<B, 64, 0, stream>>>(logp, targets, input_lens,
                                                target_lens, out);
    }
}

// Round 6
// 249.057 us; speedup vs baseline: 6.6129x; 1.2373x over previous
//
#include <hip/hip_runtime.h>
#include <hip/hip_cooperative_groups.h>

// CTC loss forward, sum over batch — single COOPERATIVE kernel, v3.
//
// Round-4 (worked): coop 256 blocks x 256 thr = 4 waves/CU -> gather
// starved (658 GB/s, kernel 155 us). Round-5 (failed): 1024-block coop
// launch; a failing/deadlocking launch during graph capture kills the
// whole capture. Lesson: never attempt a launch that can fail during
// capture. Round-6: keep the PROVEN 256-block coop grid but with 1024
// threads/block (16 waves/CU, 1 block/CU — weakest co-residency
// requirement), and gate the coop path on host-side occupancy queries
// (capture-safe) BEFORE launching.
//   - phase 1: 4096 waves stage emissions (128 waves per b, 8 rows each,
//     one 24-independent-load gather batch per wave); XCD-local mapping
//     b = blockIdx.x % 32 keeps each b's 816 KB slice in its XCD's L2
//   - grid.sync()
//   - phase 2: wave 0 of blocks 0..31 runs the serial alpha recurrence
//     (identical numerics to verified round-2: fp32 ring PFD=16, exact
//     pow2 rescale after steps s%16==0)
//   - grid.sync(); block 0 writes the deterministic ordered sum
// Fallback: proven round-2 two-kernel path.

namespace cg = cooperative_groups;

constexpr int T = 1000, B = 32, C = 1000, S = 100;
constexpr int L = 2 * S + 1;      // 201
constexpr int RS = 204;           // row stride (floats) = 816 B, 16B-aligned
constexpr int PFD = 16;           // prefetch ring depth (recurrence)
constexpr int RROWS = T + PFD;    // pad rows so the ring prefetch stays in-bounds
constexpr float OFF = 7.0f;       // emission log-offset
constexpr float LOG2E = 1.4426950408889634f;
constexpr float LN2 = 0.6931471805599453f;

constexpr int GBLK = 256;         // cooperative grid blocks (1 per CU)
constexpr int BTHR = 1024;        // threads per block (16 waves)
constexpr int WPB = BTHR / 64;    // 16 waves per block
constexpr int WAVES_PER_B = GBLK * WPB / B;                // 128
constexpr int TSEG = (T + WAVES_PER_B - 1) / WAVES_PER_B;  // 8 rows per wave

constexpr size_t DATA_WORDS = (size_t)B * RROWS * RS;  // ~26.5 MB of floats

// DPP wave_shr:1 — lane i reads lane i-1; lane 0 gets 0 (bound_ctrl).
__device__ __forceinline__ float dpp_shr1(float x) {
    return __int_as_float(
        __builtin_amdgcn_update_dpp(0, __float_as_int(x), 0x138, 0xF, 0xF, true));
}

// Wave-wide max of NONNEGATIVE values via gfx9 DPP ladder; result uniform.
__device__ __forceinline__ float wave_max_nonneg(float x) {
#define DPP_MAX(ctrl)                                                        \
    x = fmaxf(x, __int_as_float(__builtin_amdgcn_update_dpp(                 \
                     0, __float_as_int(x), (ctrl), 0xF, 0xF, true)))
    DPP_MAX(0x111);  // row_shr:1
    DPP_MAX(0x112);  // row_shr:2
    DPP_MAX(0x114);  // row_shr:4
    DPP_MAX(0x118);  // row_shr:8
    DPP_MAX(0x142);  // row_bcast15
    DPP_MAX(0x143);  // row_bcast31 -> lane63 holds wave max
#undef DPP_MAX
    return __int_as_float(__builtin_amdgcn_readlane(__float_as_int(x), 63));
}

// ---- shared recurrence body (identical numerics to verified round-2) ----
__device__ float ctc_wave_loss(const float* __restrict__ pw,
                               const int* __restrict__ targets, int b, int Tb,
                               int tl, int lane) {
    const int col = (lane <= 50) ? 4 * lane : 200;

    float m1 = 0.f, m3 = 0.f;
    if (lane <= 50) {
        const int l1 = col + 1;
        if (l1 >= 3 && l1 < L) {
            const int s = (l1 - 1) >> 1;
            if (targets[b * S + s] != targets[b * S + s - 1]) m1 = 1.f;
        }
        const int l3 = col + 3;
        if (l3 >= 3 && l3 < L) {
            const int s = (l3 - 1) >> 1;
            if (targets[b * S + s] != targets[b * S + s - 1]) m3 = 1.f;
        }
    }

    float a0 = 0.f, a1 = 0.f, a2 = 0.f, a3 = 0.f;
    {
        const float4 q0 = *reinterpret_cast<const float4*>(pw + col);
        if (lane == 0) { a0 = q0.x; a1 = q0.y; }
    }
    int esum = 0;

    // Dead-lane invariant: lane 50's cols 201..203 staged 0 -> its a1..a3
    // stay 0; lanes 51+ start 0 and only ever receive lane 50's zero a3.
#define CTC_STEP(Q_)                                  \
    do {                                              \
        const float am1 = dpp_shr1(a3);               \
        const float s01 = a0 + a1;                    \
        const float s23 = a2 + a3;                    \
        const float n0 = (a0 + am1) * (Q_).x;         \
        const float n1 = fmaf(am1, m1, s01) * (Q_).y; \
        const float n2 = (a1 + a2) * (Q_).z;          \
        const float n3 = fmaf(a1, m3, s23) * (Q_).w;  \
        a0 = n0; a1 = n1; a2 = n2; a3 = n3;           \
    } while (0)

#define CTC_RESCALE()                                                          \
    do {                                                                       \
        const float mx = wave_max_nonneg(fmaxf(fmaxf(a0, a1), fmaxf(a2, a3))); \
        const unsigned bits = __float_as_uint(mx);                             \
        if (bits != 0u) {                                                      \
            const int e = (int)((bits >> 23) & 0xFFu) - 127;                   \
            const float sc = __uint_as_float((unsigned)(127 - e) << 23);       \
            a0 *= sc; a1 *= sc; a2 *= sc; a3 *= sc;                            \
            esum += e;                                                         \
        }                                                                      \
    } while (0)

    // prefetch ring: P[i] holds the emission row (float4) for step t+i
    float4 P[PFD];
    {
        const float* pf0 = pw + (size_t)RS + col;
#pragma unroll
        for (int i = 0; i < PFD; ++i)
            P[i] = *reinterpret_cast<const float4*>(pf0 + (size_t)i * RS);
    }
    const float* pf = pw + (size_t)(PFD + 1) * RS + col;  // next row to fetch

    int t = 1;
    while (t + PFD <= Tb) {
#pragma unroll
        for (int i = 0; i < PFD; ++i) {
            const float4 q = P[i];
            P[i] = *reinterpret_cast<const float4*>(pf);  // PFD steps ahead
            pf += RS;
            CTC_STEP(q);
            // rescale after steps s%16==0 — same cadence as verified round-2
            if (((t + i) & 15) == 0) CTC_RESCALE();
        }
        t += PFD;
    }
    // tail (< PFD steps)
    {
        const int rem = Tb - t;
#pragma unroll
        for (int i = 0; i < PFD; ++i) {
            if (i < rem) {
                const float4 q = P[i];
                CTC_STEP(q);
                if (((t + i) & 15) == 0) CTC_RESCALE();
            }
        }
    }
#undef CTC_STEP
#undef CTC_RESCALE

    const int e1 = 2 * tl, e2 = 2 * tl - 1;
    float contrib = 0.f;
    if (lane <= 50) {
        if (col + 0 == e1 || col + 0 == e2) contrib += a0;
        if (col + 1 == e1 || col + 1 == e2) contrib += a1;
        if (col + 2 == e1 || col + 2 == e2) contrib += a2;
        if (col + 3 == e1 || col + 3 == e2) contrib += a3;
    }
#pragma unroll
    for (int off = 32; off; off >>= 1) contrib += __shfl_xor(contrib, off);

    const float logalpha = logf(contrib) + (float)esum * LN2 - OFF * (float)Tb;
    float loss = -logalpha;
    if (!(loss < 0.5e30f)) loss = 0.f;  // zero_infinity (catches NaN/inf)
    return loss;
}

// ---------------- cooperative fused kernel ----------------
__global__ void __launch_bounds__(BTHR, 4) ctc_coop_kernel(
        const float* __restrict__ logp, const int* __restrict__ targets,
        const int* __restrict__ input_lens, const int* __restrict__ target_lens,
        float* __restrict__ ws, float* __restrict__ out) {
    const int lane = threadIdx.x & 63;
    const int wv = threadIdx.x >> 6;
    float* loss_slot = ws + DATA_WORDS;  // [B]

    // ---------------- phase 1: stage emissions (XCD-local) ----------------
    {
        const int x = blockIdx.x;
        const int b = x & (B - 1);             // XCD of x == XCD of block b
        const int seg = (x >> 5) * WPB + wv;   // 0..127
        const int t0 = seg * TSEG;
        const int t1 = min(t0 + TSEG, T);
        const int col = 4 * lane;
        const bool ln = (lane <= 50);
        const bool h1 = ln && (col + 1 < L);   // lane <= 49
        const bool h3 = ln && (col + 3 < L);   // lane <= 49
        const int c1 = h1 ? targets[b * S + 2 * lane] : 0;
        const int c3 = h3 ? targets[b * S + 2 * lane + 1] : 0;
        float* wb = ws + (size_t)b * RROWS * RS;

        for (int t = t0; t < t1; t += 8) {
            const int n = min(8, t1 - t);  // wave-uniform (8 in this config)
            float f0[8], fa[8], fb[8];
            // gather: up to 24 independent scattered loads in flight
#pragma unroll
            for (int j = 0; j < 8; ++j) {
                if (j < n) {
                    const float* row = logp + ((size_t)(t + j) * B + b) * C;
                    f0[j] = row[0];
                    fa[j] = h1 ? row[c1] : 0.f;
                    fb[j] = h3 ? row[c3] : 0.f;
                }
            }
            // compute + store
#pragma unroll
            for (int j = 0; j < 8; ++j) {
                if (j < n && ln) {
                    const float pb = exp2f((f0[j] + OFF) * LOG2E);
                    const float p1 = h1 ? exp2f((fa[j] + OFF) * LOG2E) : 0.f;
                    const float p3 = h3 ? exp2f((fb[j] + OFF) * LOG2E) : 0.f;
                    float4 v;
                    v.x = pb;                        // even col, always < L
                    v.y = p1;                        // 0 on lane-50 pad
                    v.z = (col + 2 < L) ? pb : 0.f;  // 0 on lane-50 pad
                    v.w = p3;                        // 0 on lane-50 pad
                    *reinterpret_cast<float4*>(wb + (size_t)(t + j) * RS + col) = v;
                }
            }
        }
    }

    cg::this_grid().sync();

    // ---------------- phase 2: recurrence (32 waves total) ----------------
    if (blockIdx.x < (unsigned)B && wv == 0) {
        const int b = blockIdx.x;  // same XCD as b's staged L2 slice
        const int Tb = min(input_lens[b], T);
        const int tl = target_lens[b];
        const float* pw = ws + (size_t)b * RROWS * RS;
        const float loss = ctc_wave_loss(pw, targets, b, Tb, tl, lane);
        if (lane == 0) loss_slot[b] = loss;
    }

    cg::this_grid().sync();

    // ---------------- phase 3: deterministic ordered sum ----------------
    if (blockIdx.x == 0 && threadIdx.x == 0) {
        float s = 0.f;
        for (int i = 0; i < B; ++i) s += loss_slot[i];
        out[0] = s;  // full overwrite — no out-memset dispatch needed
    }
}

// ------------- fallback path A: round-2 two-kernel (proven) -------------
__global__ void __launch_bounds__(256) stage_kernel(
        const float* __restrict__ logp, const int* __restrict__ targets,
        float* __restrict__ ws) {
    const int t = blockIdx.x * 4 + (threadIdx.x >> 6);
    const int b = blockIdx.y;
    const int lane = threadIdx.x & 63;
    if (lane > 50) return;
    const int col = 4 * lane;
    const float* row = logp + ((size_t)t * B + b) * C;

    const float pb = exp2f((row[0] + OFF) * LOG2E);
    float p1 = 0.f, p3 = 0.f;
    const int l1 = col + 1;
    if (l1 < L) p1 = exp2f((row[targets[b * S + (l1 >> 1)]] + OFF) * LOG2E);
    const int l3 = col + 3;
    if (l3 < L) p3 = exp2f((row[targets[b * S + (l3 >> 1)]] + OFF) * LOG2E);

    float4 v;
    v.x = pb;
    v.y = p1;
    v.z = (col + 2 < L) ? pb : 0.f;
    v.w = p3;
    *reinterpret_cast<float4*>(ws + ((size_t)b * RROWS + t) * RS + col) = v;
}

__global__ void __launch_bounds__(64, 1) ctc_kernel(
        const float* __restrict__ ws, const int* __restrict__ targets,
        const int* __restrict__ input_lens, const int* __restrict__ target_lens,
        float* __restrict__ out) {
    const int b = blockIdx.x;
    const int lane = threadIdx.x;
    const int Tb = min(input_lens[b], T);
    const int tl = target_lens[b];
    const float* pw = ws + (size_t)b * RROWS * RS;
    const float loss = ctc_wave_loss(pw, targets, b, Tb, tl, lane);
    if (lane == 0) atomicAdd(out, loss);
}

// ------------- fallback path B: direct gather (ws too small) -------------
__global__ void __launch_bounds__(64, 1) ctc_direct_kernel(
        const float* __restrict__ logp, const int* __restrict__ targets,
        const int* __restrict__ input_lens, const int* __restrict__ target_lens,
        float* __restrict__ out) {
    const int b = blockIdx.x;
    const int lane = threadIdx.x;
    const int col = (lane <= 50) ? 4 * lane : 200;
    const int Tb = input_lens[b];
    const int tl = target_lens[b];

    int cc[4]; float mm[4], pm[4];
#pragma unroll
    for (int i = 0; i < 4; ++i) {
        const int l = col + i;
        const bool real = (lane <= 50) && (l < L);
        pm[i] = real ? 1.f : 0.f;
        cc[i] = real ? ((l & 1) ? targets[b * S + (l >> 1)] : 0) : 0;
        float mk = 0.f;
        if (real && (l & 1) && l >= 3) {
            const int s = (l - 1) >> 1;
            if (targets[b * S + s] != targets[b * S + s - 1]) mk = 1.f;
        }
        mm[i] = mk;
    }
    const float m1 = mm[1], m3 = mm[3];

    float a0 = 0.f, a1 = 0.f, a2 = 0.f, a3 = 0.f;
    {
        const float* rowp = logp + (size_t)b * C;
        const float p0 = pm[0] * exp2f((rowp[cc[0]] + OFF) * LOG2E);
        const float p1 = pm[1] * exp2f((rowp[cc[1]] + OFF) * LOG2E);
        if (lane == 0) { a0 = p0; a1 = p1; }
    }
    int esum = 0;

    for (int t = 1; t < Tb; ++t) {
        const float* rowp = logp + ((size_t)t * B + b) * C;
        const float p0 = pm[0] * exp2f((rowp[cc[0]] + OFF) * LOG2E);
        const float p1 = pm[1] * exp2f((rowp[cc[1]] + OFF) * LOG2E);
        const float p2 = pm[2] * exp2f((rowp[cc[2]] + OFF) * LOG2E);
        const float p3 = pm[3] * exp2f((rowp[cc[3]] + OFF) * LOG2E);
        const float am1 = dpp_shr1(a3);
        const float n0 = (a0 + am1) * p0;
        const float n1 = fmaf(am1, m1, a0 + a1) * p1;
        const float n2 = (a1 + a2) * p2;
        const float n3 = fmaf(a1, m3, a2 + a3) * p3;
        a0 = n0; a1 = n1; a2 = n2; a3 = n3;
        if ((t & 15) == 0) {
            const float mx = wave_max_nonneg(fmaxf(fmaxf(a0, a1), fmaxf(a2, a3)));
            const unsigned bits = __float_as_uint(mx);
            if (bits != 0u) {
                const int e = (int)((bits >> 23) & 0xFFu) - 127;
                const float sc = __uint_as_float((unsigned)(127 - e) << 23);
                a0 *= sc; a1 *= sc; a2 *= sc; a3 *= sc;
                esum += e;
            }
        }
    }

    const int e1 = 2 * tl, e2 = 2 * tl - 1;
    float contrib = 0.f;
    if (lane <= 50) {
        if (col + 0 == e1 || col + 0 == e2) contrib += a0;
        if (col + 1 == e1 || col + 1 == e2) contrib += a1;
        if (col + 2 == e1 || col + 2 == e2) contrib += a2;
        if (col + 3 == e1 || col + 3 == e2) contrib += a3;
    }
#pragma unroll
    for (int off = 32; off; off >>= 1) contrib += __shfl_xor(contrib, off);
    if (lane == 0) {
        const float logalpha = logf(contrib) + (float)esum * LN2 - OFF * (float)Tb;
        float loss = -logalpha;
        if (!(loss < 0.5e30f)) loss = 0.f;
        atomicAdd(out, loss);
    }
}

extern "C" void kernel_launch(void* const* d_in, const int* in_sizes, int n_in,
                              void* d_out, int out_size, void* d_ws, size_t ws_size,
                              hipStream_t stream) {
    (void)in_sizes; (void)n_in; (void)out_size;
    const float* logp = (const float*)d_in[0];
    const int* targets = (const int*)d_in[1];
    const int* input_lens = (const int*)d_in[2];
    const int* target_lens = (const int*)d_in[3];
    float* out = (float*)d_out;
    float* ws = (float*)d_ws;

    // One-time, capture-safe host queries: decide the coop path WITHOUT ever
    // issuing a launch that could fail during graph capture (round-5 lesson).
    static int s_coop = -1;
    if (s_coop < 0) {
        int nb = 0, ncu = 0, dev = 0, coopOk = 0;
        hipError_t e = hipGetDevice(&dev);
        if (e == hipSuccess)
            e = hipDeviceGetAttribute(&coopOk, hipDeviceAttributeCooperativeLaunch,
                                      dev);
        if (e == hipSuccess)
            e = hipDeviceGetAttribute(&ncu, hipDeviceAttributeMultiprocessorCount,
                                      dev);
        if (e == hipSuccess)
            e = hipOccupancyMaxActiveBlocksPerMultiprocessor(&nb, ctc_coop_kernel,
                                                             BTHR, 0);
        s_coop = (e == hipSuccess && coopOk && nb >= 1 &&
                  (long long)nb * ncu >= GBLK)
                     ? 1
                     : 0;
    }

    const size_t ws_needed = (DATA_WORDS + (size_t)B) * sizeof(float);
    if (ws_size >= ws_needed && s_coop == 1) {
        void* args[] = {(void*)&logp, (void*)&targets, (void*)&input_lens,
                        (void*)&target_lens, (void*)&ws, (void*)&out};
        const hipError_t err = hipLaunchCooperativeKernel(
            (const void*)ctc_coop_kernel, dim3(GBLK), dim3(BTHR), args, 0, stream);
        if (err == hipSuccess) return;
        s_coop = 0;  // never try again; fall through to the proven path
    }
    if (ws_size >= ws_needed) {
        hipMemsetAsync(d_out, 0, sizeof(float), stream);
        dim3 gA(T / 4, B);
        stage_kernel<<<gA, 256, 0, stream>>>(logp, targets, ws);
        ctc_kernel<<<B, 64, 0, stream>>>(ws, targets, input_lens, target_lens, out);
    } else {
        hipMemsetAsync(d_out, 0, sizeof(float), stream);
        ctc_direct_kernel<<<B, 64, 0, stream>>>(logp, targets, input_lens,
                                                target_lens, out);
    }
}

// Round 7
// 245.287 us; speedup vs baseline: 6.7146x; 1.0154x over previous
//
#include <hip/hip_runtime.h>
#include <hip/hip_cooperative_groups.h>

// CTC loss forward, sum over batch — single COOPERATIVE kernel, v4.
//
// Round-6 falsifier fired: the scattered 4B gather is pinned at ~0.6-1.3
// TB/s regardless of parallelism (r1: 397 GB/s @480 waves, r4: 658 @1024,
// r6: 640 @4096). Each scattered wave-load (~50 random addresses in a 4KB
// row) costs ~35 line transactions for ~200 useful bytes — address-path
// bound, not HBM bound. Fix: NEVER gather from global. Each wave streams
// one full 4KB logp row COALESCED (float4 — the proven 6.3 TB/s pattern)
// into its own private 4KB LDS slice (no barriers), gathers the ~102
// needed columns from LDS (random LDS reads ~2-way conflicts, free),
// exponentiates, stores the 816B ws row coalesced.
//   - 256 blocks x 1024 thr (16 waves, 64KB LDS, 1 block/CU)
//   - XCD-local: block x handles b = x%32 -> b's ws slice lives in the
//     XCD L2 where consumer block b runs phase 2
//   - phase 2: wave 0 of blocks 0..31 runs the serial alpha recurrence
//     (identical numerics to verified rounds 2/6: fp32 ring PFD=16,
//     exact pow2 rescale after steps s%16==0)
//   - grid.sync(); block 0 writes the deterministic ordered sum
// Host-side occupancy gating (round-5 lesson: never issue a launch that
// can fail during graph capture). Fallback: proven round-2 two-kernel path.

namespace cg = cooperative_groups;

constexpr int T = 1000, B = 32, C = 1000, S = 100;
constexpr int L = 2 * S + 1;      // 201
constexpr int RS = 204;           // row stride (floats) = 816 B, 16B-aligned
constexpr int PFD = 16;           // prefetch ring depth (recurrence)
constexpr int RROWS = T + PFD;    // pad rows so the ring prefetch stays in-bounds
constexpr float OFF = 7.0f;       // emission log-offset
constexpr float LOG2E = 1.4426950408889634f;
constexpr float LN2 = 0.6931471805599453f;

constexpr int GBLK = 256;         // cooperative grid blocks (1 per CU)
constexpr int BTHR = 1024;        // threads per block (16 waves)
constexpr int WPB = BTHR / 64;    // 16 waves per block
constexpr int SLICES = GBLK / B;  // 8 t-slices per batch element
constexpr int TSL = T / SLICES;   // 125 rows per block

constexpr size_t DATA_WORDS = (size_t)B * RROWS * RS;  // ~26.5 MB of floats

// DPP wave_shr:1 — lane i reads lane i-1; lane 0 gets 0 (bound_ctrl).
__device__ __forceinline__ float dpp_shr1(float x) {
    return __int_as_float(
        __builtin_amdgcn_update_dpp(0, __float_as_int(x), 0x138, 0xF, 0xF, true));
}

// Wave-wide max of NONNEGATIVE values via gfx9 DPP ladder; result uniform.
__device__ __forceinline__ float wave_max_nonneg(float x) {
#define DPP_MAX(ctrl)                                                        \
    x = fmaxf(x, __int_as_float(__builtin_amdgcn_update_dpp(                 \
                     0, __float_as_int(x), (ctrl), 0xF, 0xF, true)))
    DPP_MAX(0x111);  // row_shr:1
    DPP_MAX(0x112);  // row_shr:2
    DPP_MAX(0x114);  // row_shr:4
    DPP_MAX(0x118);  // row_shr:8
    DPP_MAX(0x142);  // row_bcast15
    DPP_MAX(0x143);  // row_bcast31 -> lane63 holds wave max
#undef DPP_MAX
    return __int_as_float(__builtin_amdgcn_readlane(__float_as_int(x), 63));
}

// ---- shared recurrence body (identical numerics to verified round-2/6) ----
__device__ float ctc_wave_loss(const float* __restrict__ pw,
                               const int* __restrict__ targets, int b, int Tb,
                               int tl, int lane) {
    const int col = (lane <= 50) ? 4 * lane : 200;

    float m1 = 0.f, m3 = 0.f;
    if (lane <= 50) {
        const int l1 = col + 1;
        if (l1 >= 3 && l1 < L) {
            const int s = (l1 - 1) >> 1;
            if (targets[b * S + s] != targets[b * S + s - 1]) m1 = 1.f;
        }
        const int l3 = col + 3;
        if (l3 >= 3 && l3 < L) {
            const int s = (l3 - 1) >> 1;
            if (targets[b * S + s] != targets[b * S + s - 1]) m3 = 1.f;
        }
    }

    float a0 = 0.f, a1 = 0.f, a2 = 0.f, a3 = 0.f;
    {
        const float4 q0 = *reinterpret_cast<const float4*>(pw + col);
        if (lane == 0) { a0 = q0.x; a1 = q0.y; }
    }
    int esum = 0;

    // Dead-lane invariant: lane 50's cols 201..203 staged 0 -> its a1..a3
    // stay 0; lanes 51+ start 0 and only ever receive lane 50's zero a3.
#define CTC_STEP(Q_)                                  \
    do {                                              \
        const float am1 = dpp_shr1(a3);               \
        const float s01 = a0 + a1;                    \
        const float s23 = a2 + a3;                    \
        const float n0 = (a0 + am1) * (Q_).x;         \
        const float n1 = fmaf(am1, m1, s01) * (Q_).y; \
        const float n2 = (a1 + a2) * (Q_).z;          \
        const float n3 = fmaf(a1, m3, s23) * (Q_).w;  \
        a0 = n0; a1 = n1; a2 = n2; a3 = n3;           \
    } while (0)

#define CTC_RESCALE()                                                          \
    do {                                                                       \
        const float mx = wave_max_nonneg(fmaxf(fmaxf(a0, a1), fmaxf(a2, a3))); \
        const unsigned bits = __float_as_uint(mx);                             \
        if (bits != 0u) {                                                      \
            const int e = (int)((bits >> 23) & 0xFFu) - 127;                   \
            const float sc = __uint_as_float((unsigned)(127 - e) << 23);       \
            a0 *= sc; a1 *= sc; a2 *= sc; a3 *= sc;                            \
            esum += e;                                                         \
        }                                                                      \
    } while (0)

    // prefetch ring: P[i] holds the emission row (float4) for step t+i
    float4 P[PFD];
    {
        const float* pf0 = pw + (size_t)RS + col;
#pragma unroll
        for (int i = 0; i < PFD; ++i)
            P[i] = *reinterpret_cast<const float4*>(pf0 + (size_t)i * RS);
    }
    const float* pf = pw + (size_t)(PFD + 1) * RS + col;  // next row to fetch

    int t = 1;
    while (t + PFD <= Tb) {
#pragma unroll
        for (int i = 0; i < PFD; ++i) {
            const float4 q = P[i];
            P[i] = *reinterpret_cast<const float4*>(pf);  // PFD steps ahead
            pf += RS;
            CTC_STEP(q);
            // rescale after steps s%16==0 — same cadence as verified round-2
            if (((t + i) & 15) == 0) CTC_RESCALE();
        }
        t += PFD;
    }
    // tail (< PFD steps)
    {
        const int rem = Tb - t;
#pragma unroll
        for (int i = 0; i < PFD; ++i) {
            if (i < rem) {
                const float4 q = P[i];
                CTC_STEP(q);
                if (((t + i) & 15) == 0) CTC_RESCALE();
            }
        }
    }
#undef CTC_STEP
#undef CTC_RESCALE

    const int e1 = 2 * tl, e2 = 2 * tl - 1;
    float contrib = 0.f;
    if (lane <= 50) {
        if (col + 0 == e1 || col + 0 == e2) contrib += a0;
        if (col + 1 == e1 || col + 1 == e2) contrib += a1;
        if (col + 2 == e1 || col + 2 == e2) contrib += a2;
        if (col + 3 == e1 || col + 3 == e2) contrib += a3;
    }
#pragma unroll
    for (int off = 32; off; off >>= 1) contrib += __shfl_xor(contrib, off);

    const float logalpha = logf(contrib) + (float)esum * LN2 - OFF * (float)Tb;
    float loss = -logalpha;
    if (!(loss < 0.5e30f)) loss = 0.f;  // zero_infinity (catches NaN/inf)
    return loss;
}

// ---------------- cooperative fused kernel ----------------
__global__ void __launch_bounds__(BTHR, 4) ctc_coop_kernel(
        const float* __restrict__ logp, const int* __restrict__ targets,
        const int* __restrict__ input_lens, const int* __restrict__ target_lens,
        float* __restrict__ ws, float* __restrict__ out) {
    __shared__ float rowbuf[WPB][C];  // 16 x 4000 B = 64 KB, wave-private rows
    const int lane = threadIdx.x & 63;
    const int wv = threadIdx.x >> 6;
    float* loss_slot = ws + DATA_WORDS;  // [B]

    // ------- phase 1: coalesced row read -> LDS -> gather -> ws -------
    {
        const int x = blockIdx.x;
        const int b = x & (B - 1);            // XCD of x == XCD of block b
        const int t0 = (x >> 5) * TSL;        // this block's 125-row slice
        const int col = 4 * lane;
        const bool ln = (lane <= 50);
        const bool h1 = ln && (col + 1 < L);  // lane <= 49
        const bool h3 = ln && (col + 3 < L);  // lane <= 49
        const int c1 = h1 ? targets[b * S + 2 * lane] : 0;
        const int c3 = h3 ? targets[b * S + 2 * lane + 1] : 0;
        float* wb = ws + (size_t)b * RROWS * RS;
        float4* lrow = reinterpret_cast<float4*>(&rowbuf[wv][0]);

        for (int i = wv; i < TSL; i += WPB) {
            const int t = t0 + i;
            // coalesced stream: one 4KB row via float4 (proven 6.3 TB/s pattern)
            const float4* grow =
                reinterpret_cast<const float4*>(logp + ((size_t)t * B + b) * C);
#pragma unroll
            for (int k = 0; k < 4; ++k) {
                const int idx = k * 64 + lane;
                if (idx < C / 4) lrow[idx] = grow[idx];
            }
            // gather from own LDS slice (wave-private -> no barrier needed;
            // compiler inserts the lgkmcnt between ds_write and ds_read)
            if (ln) {
                const float pb = exp2f((rowbuf[wv][0] + OFF) * LOG2E);
                const float p1 =
                    h1 ? exp2f((rowbuf[wv][c1] + OFF) * LOG2E) : 0.f;
                const float p3 =
                    h3 ? exp2f((rowbuf[wv][c3] + OFF) * LOG2E) : 0.f;
                float4 v;
                v.x = pb;                        // even col, always < L
                v.y = p1;                        // 0 on lane-50 pad
                v.z = (col + 2 < L) ? pb : 0.f;  // 0 on lane-50 pad
                v.w = p3;                        // 0 on lane-50 pad
                *reinterpret_cast<float4*>(wb + (size_t)t * RS + col) = v;
            }
        }
    }

    cg::this_grid().sync();

    // ---------------- phase 2: recurrence (32 waves total) ----------------
    if (blockIdx.x < (unsigned)B && wv == 0) {
        const int b = blockIdx.x;  // same XCD as b's staged L2 slice
        const int Tb = min(input_lens[b], T);
        const int tl = target_lens[b];
        const float* pw = ws + (size_t)b * RROWS * RS;
        const float loss = ctc_wave_loss(pw, targets, b, Tb, tl, lane);
        if (lane == 0) loss_slot[b] = loss;
    }

    cg::this_grid().sync();

    // ---------------- phase 3: deterministic ordered sum ----------------
    if (blockIdx.x == 0 && threadIdx.x == 0) {
        float s = 0.f;
        for (int i = 0; i < B; ++i) s += loss_slot[i];
        out[0] = s;  // full overwrite — no out-memset dispatch needed
    }
}

// ------------- fallback path A: round-2 two-kernel (proven) -------------
__global__ void __launch_bounds__(256) stage_kernel(
        const float* __restrict__ logp, const int* __restrict__ targets,
        float* __restrict__ ws) {
    const int t = blockIdx.x * 4 + (threadIdx.x >> 6);
    const int b = blockIdx.y;
    const int lane = threadIdx.x & 63;
    if (lane > 50) return;
    const int col = 4 * lane;
    const float* row = logp + ((size_t)t * B + b) * C;

    const float pb = exp2f((row[0] + OFF) * LOG2E);
    float p1 = 0.f, p3 = 0.f;
    const int l1 = col + 1;
    if (l1 < L) p1 = exp2f((row[targets[b * S + (l1 >> 1)]] + OFF) * LOG2E);
    const int l3 = col + 3;
    if (l3 < L) p3 = exp2f((row[targets[b * S + (l3 >> 1)]] + OFF) * LOG2E);

    float4 v;
    v.x = pb;
    v.y = p1;
    v.z = (col + 2 < L) ? pb : 0.f;
    v.w = p3;
    *reinterpret_cast<float4*>(ws + ((size_t)b * RROWS + t) * RS + col) = v;
}

__global__ void __launch_bounds__(64, 1) ctc_kernel(
        const float* __restrict__ ws, const int* __restrict__ targets,
        const int* __restrict__ input_lens, const int* __restrict__ target_lens,
        float* __restrict__ out) {
    const int b = blockIdx.x;
    const int lane = threadIdx.x;
    const int Tb = min(input_lens[b], T);
    const int tl = target_lens[b];
    const float* pw = ws + (size_t)b * RROWS * RS;
    const float loss = ctc_wave_loss(pw, targets, b, Tb, tl, lane);
    if (lane == 0) atomicAdd(out, loss);
}

// ------------- fallback path B: direct gather (ws too small) -------------
__global__ void __launch_bounds__(64, 1) ctc_direct_kernel(
        const float* __restrict__ logp, const int* __restrict__ targets,
        const int* __restrict__ input_lens, const int* __restrict__ target_lens,
        float* __restrict__ out) {
    const int b = blockIdx.x;
    const int lane = threadIdx.x;
    const int col = (lane <= 50) ? 4 * lane : 200;
    const int Tb = input_lens[b];
    const int tl = target_lens[b];

    int cc[4]; float mm[4], pm[4];
#pragma unroll
    for (int i = 0; i < 4; ++i) {
        const int l = col + i;
        const bool real = (lane <= 50) && (l < L);
        pm[i] = real ? 1.f : 0.f;
        cc[i] = real ? ((l & 1) ? targets[b * S + (l >> 1)] : 0) : 0;
        float mk = 0.f;
        if (real && (l & 1) && l >= 3) {
            const int s = (l - 1) >> 1;
            if (targets[b * S + s] != targets[b * S + s - 1]) mk = 1.f;
        }
        mm[i] = mk;
    }
    const float m1 = mm[1], m3 = mm[3];

    float a0 = 0.f, a1 = 0.f, a2 = 0.f, a3 = 0.f;
    {
        const float* rowp = logp + (size_t)b * C;
        const float p0 = pm[0] * exp2f((rowp[cc[0]] + OFF) * LOG2E);
        const float p1 = pm[1] * exp2f((rowp[cc[1]] + OFF) * LOG2E);
        if (lane == 0) { a0 = p0; a1 = p1; }
    }
    int esum = 0;

    for (int t = 1; t < Tb; ++t) {
        const float* rowp = logp + ((size_t)t * B + b) * C;
        const float p0 = pm[0] * exp2f((rowp[cc[0]] + OFF) * LOG2E);
        const float p1 = pm[1] * exp2f((rowp[cc[1]] + OFF) * LOG2E);
        const float p2 = pm[2] * exp2f((rowp[cc[2]] + OFF) * LOG2E);
        const float p3 = pm[3] * exp2f((rowp[cc[3]] + OFF) * LOG2E);
        const float am1 = dpp_shr1(a3);
        const float n0 = (a0 + am1) * p0;
        const float n1 = fmaf(am1, m1, a0 + a1) * p1;
        const float n2 = (a1 + a2) * p2;
        const float n3 = fmaf(a1, m3, a2 + a3) * p3;
        a0 = n0; a1 = n1; a2 = n2; a3 = n3;
        if ((t & 15) == 0) {
            const float mx = wave_max_nonneg(fmaxf(fmaxf(a0, a1), fmaxf(a2, a3)));
            const unsigned bits = __float_as_uint(mx);
            if (bits != 0u) {
                const int e = (int)((bits >> 23) & 0xFFu) - 127;
                const float sc = __uint_as_float((unsigned)(127 - e) << 23);
                a0 *= sc; a1 *= sc; a2 *= sc; a3 *= sc;
                esum += e;
            }
        }
    }

    const int e1 = 2 * tl, e2 = 2 * tl - 1;
    float contrib = 0.f;
    if (lane <= 50) {
        if (col + 0 == e1 || col + 0 == e2) contrib += a0;
        if (col + 1 == e1 || col + 1 == e2) contrib += a1;
        if (col + 2 == e1 || col + 2 == e2) contrib += a2;
        if (col + 3 == e1 || col + 3 == e2) contrib += a3;
    }
#pragma unroll
    for (int off = 32; off; off >>= 1) contrib += __shfl_xor(contrib, off);
    if (lane == 0) {
        const float logalpha = logf(contrib) + (float)esum * LN2 - OFF * (float)Tb;
        float loss = -logalpha;
        if (!(loss < 0.5e30f)) loss = 0.f;
        atomicAdd(out, loss);
    }
}

extern "C" void kernel_launch(void* const* d_in, const int* in_sizes, int n_in,
                              void* d_out, int out_size, void* d_ws, size_t ws_size,
                              hipStream_t stream) {
    (void)in_sizes; (void)n_in; (void)out_size;
    const float* logp = (const float*)d_in[0];
    const int* targets = (const int*)d_in[1];
    const int* input_lens = (const int*)d_in[2];
    const int* target_lens = (const int*)d_in[3];
    float* out = (float*)d_out;
    float* ws = (float*)d_ws;

    // One-time, capture-safe host queries: decide the coop path WITHOUT ever
    // issuing a launch that could fail during graph capture (round-5 lesson).
    static int s_coop = -1;
    if (s_coop < 0) {
        int nb = 0, ncu = 0, dev = 0, coopOk = 0;
        hipError_t e = hipGetDevice(&dev);
        if (e == hipSuccess)
            e = hipDeviceGetAttribute(&coopOk, hipDeviceAttributeCooperativeLaunch,
                                      dev);
        if (e == hipSuccess)
            e = hipDeviceGetAttribute(&ncu, hipDeviceAttributeMultiprocessorCount,
                                      dev);
        if (e == hipSuccess)
            e = hipOccupancyMaxActiveBlocksPerMultiprocessor(&nb, ctc_coop_kernel,
                                                             BTHR, 0);
        s_coop = (e == hipSuccess && coopOk && nb >= 1 &&
                  (long long)nb * ncu >= GBLK)
                     ? 1
                     : 0;
    }

    const size_t ws_needed = (DATA_WORDS + (size_t)B) * sizeof(float);
    if (ws_size >= ws_needed && s_coop == 1) {
        void* args[] = {(void*)&logp, (void*)&targets, (void*)&input_lens,
                        (void*)&target_lens, (void*)&ws, (void*)&out};
        const hipError_t err = hipLaunchCooperativeKernel(
            (const void*)ctc_coop_kernel, dim3(GBLK), dim3(BTHR), args, 0, stream);
        if (err == hipSuccess) return;
        s_coop = 0;  // never try again; fall through to the proven path
    }
    if (ws_size >= ws_needed) {
        hipMemsetAsync(d_out, 0, sizeof(float), stream);
        dim3 gA(T / 4, B);
        stage_kernel<<<gA, 256, 0, stream>>>(logp, targets, ws);
        ctc_kernel<<<B, 64, 0, stream>>>(ws, targets, input_lens, target_lens, out);
    } else {
        hipMemsetAsync(d_out, 0, sizeof(float), stream);
        ctc_direct_kernel<<<B, 64, 0, stream>>>(logp, targets, input_lens,
                                                target_lens, out);
    }
}

// Round 8
// 239.425 us; speedup vs baseline: 6.8789x; 1.0245x over previous
//
#include <hip/hip_runtime.h>
#include <hip/hip_cooperative_groups.h>

// CTC loss forward, sum over batch — single COOPERATIVE kernel, v5.
//
// Round-7 diagnosis: three phase-1 rewrites (scatter@4w, scatter@16w,
// coalesced@16w) all land at 155-160 us -> phase 1 was never the
// bottleneck. VGPR_Count=60 exposed the real one: __launch_bounds__(1024,4)
// (64 waves/CU, over the 32/CU hardware cap) budgeted 64 VGPRs/wave, so the
// recurrence's float4 P[16] ring (64 VGPRs alone) SPILLED TO SCRATCH -> a
// ~L2-latency scratch round trip on every serial step (999 x ~120cyc ~= the
// invariant ~120 us). Fix: 512 threads/block, __launch_bounds__(512,1)
// -> 2 waves/SIMD -> 256-VGPR cap; ring back to PFD=32, register-resident.
//   - 256 blocks x 512 thr, 64 KB LDS, 1 block/CU
//   - phase 1: each wave streams rows coalesced (float4) into its private
//     2-row LDS slice with an explicit 2-row/8-load pipeline (64 KB in
//     flight per CU), gathers the ~102 needed cols from LDS, stores the
//     816 B ws row; XCD-local: block x handles b = x%32 so b's ws slice
//     lives in the XCD L2 where consumer block b runs phase 2
//   - phase 2: wave 0 of blocks 0..31 runs the serial recurrence
//     (identical numerics to verified r0/r2: fp32 ring PFD=32, exact pow2
//     rescale after steps s%16==0)
//   - grid.sync(); block 0 writes the deterministic ordered sum
// Host-side occupancy gating (round-5 lesson). Fallback: proven two-kernel.

namespace cg = cooperative_groups;

constexpr int T = 1000, B = 32, C = 1000, S = 100;
constexpr int L = 2 * S + 1;      // 201
constexpr int RS = 204;           // row stride (floats) = 816 B, 16B-aligned
constexpr int PFD = 32;           // prefetch ring depth (recurrence)
constexpr int RROWS = T + PFD;    // pad rows so the ring prefetch stays in-bounds
constexpr float OFF = 7.0f;       // emission log-offset
constexpr float LOG2E = 1.4426950408889634f;
constexpr float LN2 = 0.6931471805599453f;

constexpr int GBLK = 256;         // cooperative grid blocks (1 per CU)
constexpr int BTHR = 512;         // threads per block (8 waves)
constexpr int WPB = BTHR / 64;    // 8 waves per block
constexpr int SLICES = GBLK / B;  // 8 t-slices per batch element
constexpr int TSL = T / SLICES;   // 125 rows per block

constexpr size_t DATA_WORDS = (size_t)B * RROWS * RS;  // ~26.9 MB of floats

// DPP wave_shr:1 — lane i reads lane i-1; lane 0 gets 0 (bound_ctrl).
__device__ __forceinline__ float dpp_shr1(float x) {
    return __int_as_float(
        __builtin_amdgcn_update_dpp(0, __float_as_int(x), 0x138, 0xF, 0xF, true));
}

// Wave-wide max of NONNEGATIVE values via gfx9 DPP ladder; result uniform.
__device__ __forceinline__ float wave_max_nonneg(float x) {
#define DPP_MAX(ctrl)                                                        \
    x = fmaxf(x, __int_as_float(__builtin_amdgcn_update_dpp(                 \
                     0, __float_as_int(x), (ctrl), 0xF, 0xF, true)))
    DPP_MAX(0x111);  // row_shr:1
    DPP_MAX(0x112);  // row_shr:2
    DPP_MAX(0x114);  // row_shr:4
    DPP_MAX(0x118);  // row_shr:8
    DPP_MAX(0x142);  // row_bcast15
    DPP_MAX(0x143);  // row_bcast31 -> lane63 holds wave max
#undef DPP_MAX
    return __int_as_float(__builtin_amdgcn_readlane(__float_as_int(x), 63));
}

// ---- shared recurrence body (identical numerics to verified r0/r2) ----
__device__ float ctc_wave_loss(const float* __restrict__ pw,
                               const int* __restrict__ targets, int b, int Tb,
                               int tl, int lane) {
    const int col = (lane <= 50) ? 4 * lane : 200;

    float m1 = 0.f, m3 = 0.f;
    if (lane <= 50) {
        const int l1 = col + 1;
        if (l1 >= 3 && l1 < L) {
            const int s = (l1 - 1) >> 1;
            if (targets[b * S + s] != targets[b * S + s - 1]) m1 = 1.f;
        }
        const int l3 = col + 3;
        if (l3 >= 3 && l3 < L) {
            const int s = (l3 - 1) >> 1;
            if (targets[b * S + s] != targets[b * S + s - 1]) m3 = 1.f;
        }
    }

    float a0 = 0.f, a1 = 0.f, a2 = 0.f, a3 = 0.f;
    {
        const float4 q0 = *reinterpret_cast<const float4*>(pw + col);
        if (lane == 0) { a0 = q0.x; a1 = q0.y; }
    }
    int esum = 0;

    // Dead-lane invariant: lane 50's cols 201..203 staged 0 -> its a1..a3
    // stay 0; lanes 51+ start 0 and only ever receive lane 50's zero a3.
#define CTC_STEP(Q_)                                  \
    do {                                              \
        const float am1 = dpp_shr1(a3);               \
        const float s01 = a0 + a1;                    \
        const float s23 = a2 + a3;                    \
        const float n0 = (a0 + am1) * (Q_).x;         \
        const float n1 = fmaf(am1, m1, s01) * (Q_).y; \
        const float n2 = (a1 + a2) * (Q_).z;          \
        const float n3 = fmaf(a1, m3, s23) * (Q_).w;  \
        a0 = n0; a1 = n1; a2 = n2; a3 = n3;           \
    } while (0)

#define CTC_RESCALE()                                                          \
    do {                                                                       \
        const float mx = wave_max_nonneg(fmaxf(fmaxf(a0, a1), fmaxf(a2, a3))); \
        const unsigned bits = __float_as_uint(mx);                             \
        if (bits != 0u) {                                                      \
            const int e = (int)((bits >> 23) & 0xFFu) - 127;                   \
            const float sc = __uint_as_float((unsigned)(127 - e) << 23);       \
            a0 *= sc; a1 *= sc; a2 *= sc; a3 *= sc;                            \
            esum += e;                                                         \
        }                                                                      \
    } while (0)

    // prefetch ring: P[i] holds the emission row (float4) for step t+i
    float4 P[PFD];
    {
        const float* pf0 = pw + (size_t)RS + col;
#pragma unroll
        for (int i = 0; i < PFD; ++i)
            P[i] = *reinterpret_cast<const float4*>(pf0 + (size_t)i * RS);
    }
    const float* pf = pw + (size_t)(PFD + 1) * RS + col;  // next row to fetch

    int t = 1;
    while (t + PFD <= Tb) {
#pragma unroll
        for (int i = 0; i < PFD; ++i) {
            const float4 q = P[i];
            P[i] = *reinterpret_cast<const float4*>(pf);  // PFD steps ahead
            pf += RS;
            CTC_STEP(q);
            // rescale after steps s%16==0 — same cadence as all passing rounds
            if (((t + i) & 15) == 0) CTC_RESCALE();
        }
        t += PFD;
    }
    // tail (< PFD steps)
    {
        const int rem = Tb - t;
#pragma unroll
        for (int i = 0; i < PFD; ++i) {
            if (i < rem) {
                const float4 q = P[i];
                CTC_STEP(q);
                if (((t + i) & 15) == 0) CTC_RESCALE();
            }
        }
    }
#undef CTC_STEP
#undef CTC_RESCALE

    const int e1 = 2 * tl, e2 = 2 * tl - 1;
    float contrib = 0.f;
    if (lane <= 50) {
        if (col + 0 == e1 || col + 0 == e2) contrib += a0;
        if (col + 1 == e1 || col + 1 == e2) contrib += a1;
        if (col + 2 == e1 || col + 2 == e2) contrib += a2;
        if (col + 3 == e1 || col + 3 == e2) contrib += a3;
    }
#pragma unroll
    for (int off = 32; off; off >>= 1) contrib += __shfl_xor(contrib, off);

    const float logalpha = logf(contrib) + (float)esum * LN2 - OFF * (float)Tb;
    float loss = -logalpha;
    if (!(loss < 0.5e30f)) loss = 0.f;  // zero_infinity (catches NaN/inf)
    return loss;
}

// ---------------- cooperative fused kernel ----------------
__global__ void __launch_bounds__(BTHR, 1) ctc_coop_kernel(
        const float* __restrict__ logp, const int* __restrict__ targets,
        const int* __restrict__ input_lens, const int* __restrict__ target_lens,
        float* __restrict__ ws, float* __restrict__ out) {
    __shared__ float rowbuf[WPB][2][C];  // 8 waves x 2 rows x 4000 B = 64 KB
    const int lane = threadIdx.x & 63;
    const int wv = threadIdx.x >> 6;
    float* loss_slot = ws + DATA_WORDS;  // [B]

    // ------- phase 1: coalesced rows -> LDS -> gather -> ws (2-row pipe) ----
    {
        const int x = blockIdx.x;
        const int b = x & (B - 1);            // XCD of x == XCD of block b
        const int t0 = (x >> 5) * TSL;        // this block's 125-row slice
        const int col = 4 * lane;
        const bool ln = (lane <= 50);
        const bool h1 = ln && (col + 1 < L);  // lane <= 49
        const bool h3 = ln && (col + 3 < L);  // lane <= 49
        const int c1 = h1 ? targets[b * S + 2 * lane] : 0;
        const int c3 = h3 ? targets[b * S + 2 * lane + 1] : 0;
        float* wb = ws + (size_t)b * RROWS * RS;
        float4* lA = reinterpret_cast<float4*>(&rowbuf[wv][0][0]);
        float4* lB = reinterpret_cast<float4*>(&rowbuf[wv][1][0]);

        for (int i = wv; i < TSL; i += 2 * WPB) {
            const int iB = i + WPB;
            const int tA = t0 + i;
            const int tB = t0 + iB;
            const bool hasB = (iB < TSL);  // wave-uniform
            // issue 8 coalesced 1KB wave-loads (2 rows) before consuming any
            float4 ra[4], rb[4];
            {
                const float4* ga = reinterpret_cast<const float4*>(
                    logp + ((size_t)tA * B + b) * C);
#pragma unroll
                for (int k = 0; k < 4; ++k) {
                    const int idx = k * 64 + lane;
                    if (idx < C / 4) ra[k] = ga[idx];
                }
            }
            if (hasB) {
                const float4* gb = reinterpret_cast<const float4*>(
                    logp + ((size_t)tB * B + b) * C);
#pragma unroll
                for (int k = 0; k < 4; ++k) {
                    const int idx = k * 64 + lane;
                    if (idx < C / 4) rb[k] = gb[idx];
                }
            }
            // row A: LDS park -> gather -> coalesced ws store
#pragma unroll
            for (int k = 0; k < 4; ++k) {
                const int idx = k * 64 + lane;
                if (idx < C / 4) lA[idx] = ra[k];
            }
            if (ln) {
                const float pb = exp2f((rowbuf[wv][0][0] + OFF) * LOG2E);
                const float p1 = h1 ? exp2f((rowbuf[wv][0][c1] + OFF) * LOG2E) : 0.f;
                const float p3 = h3 ? exp2f((rowbuf[wv][0][c3] + OFF) * LOG2E) : 0.f;
                float4 v;
                v.x = pb;                        // even col, always < L
                v.y = p1;                        // 0 on lane-50 pad
                v.z = (col + 2 < L) ? pb : 0.f;  // 0 on lane-50 pad
                v.w = p3;                        // 0 on lane-50 pad
                *reinterpret_cast<float4*>(wb + (size_t)tA * RS + col) = v;
            }
            // row B
            if (hasB) {
#pragma unroll
                for (int k = 0; k < 4; ++k) {
                    const int idx = k * 64 + lane;
                    if (idx < C / 4) lB[idx] = rb[k];
                }
                if (ln) {
                    const float pb = exp2f((rowbuf[wv][1][0] + OFF) * LOG2E);
                    const float p1 =
                        h1 ? exp2f((rowbuf[wv][1][c1] + OFF) * LOG2E) : 0.f;
                    const float p3 =
                        h3 ? exp2f((rowbuf[wv][1][c3] + OFF) * LOG2E) : 0.f;
                    float4 v;
                    v.x = pb;
                    v.y = p1;
                    v.z = (col + 2 < L) ? pb : 0.f;
                    v.w = p3;
                    *reinterpret_cast<float4*>(wb + (size_t)tB * RS + col) = v;
                }
            }
        }
    }

    cg::this_grid().sync();

    // ---------------- phase 2: recurrence (32 waves total) ----------------
    if (blockIdx.x < (unsigned)B && wv == 0) {
        const int b = blockIdx.x;  // same XCD as b's staged L2 slice
        const int Tb = min(input_lens[b], T);
        const int tl = target_lens[b];
        const float* pw = ws + (size_t)b * RROWS * RS;
        const float loss = ctc_wave_loss(pw, targets, b, Tb, tl, lane);
        if (lane == 0) loss_slot[b] = loss;
    }

    cg::this_grid().sync();

    // ---------------- phase 3: deterministic ordered sum ----------------
    if (blockIdx.x == 0 && threadIdx.x == 0) {
        float s = 0.f;
        for (int i = 0; i < B; ++i) s += loss_slot[i];
        out[0] = s;  // full overwrite — no out-memset dispatch needed
    }
}

// ------------- fallback path A: round-2 two-kernel (proven) -------------
__global__ void __launch_bounds__(256) stage_kernel(
        const float* __restrict__ logp, const int* __restrict__ targets,
        float* __restrict__ ws) {
    const int t = blockIdx.x * 4 + (threadIdx.x >> 6);
    const int b = blockIdx.y;
    const int lane = threadIdx.x & 63;
    if (lane > 50) return;
    const int col = 4 * lane;
    const float* row = logp + ((size_t)t * B + b) * C;

    const float pb = exp2f((row[0] + OFF) * LOG2E);
    float p1 = 0.f, p3 = 0.f;
    const int l1 = col + 1;
    if (l1 < L) p1 = exp2f((row[targets[b * S + (l1 >> 1)]] + OFF) * LOG2E);
    const int l3 = col + 3;
    if (l3 < L) p3 = exp2f((row[targets[b * S + (l3 >> 1)]] + OFF) * LOG2E);

    float4 v;
    v.x = pb;
    v.y = p1;
    v.z = (col + 2 < L) ? pb : 0.f;
    v.w = p3;
    *reinterpret_cast<float4*>(ws + ((size_t)b * RROWS + t) * RS + col) = v;
}

__global__ void __launch_bounds__(64, 1) ctc_kernel(
        const float* __restrict__ ws, const int* __restrict__ targets,
        const int* __restrict__ input_lens, const int* __restrict__ target_lens,
        float* __restrict__ out) {
    const int b = blockIdx.x;
    const int lane = threadIdx.x;
    const int Tb = min(input_lens[b], T);
    const int tl = target_lens[b];
    const float* pw = ws + (size_t)b * RROWS * RS;
    const float loss = ctc_wave_loss(pw, targets, b, Tb, tl, lane);
    if (lane == 0) atomicAdd(out, loss);
}

// ------------- fallback path B: direct gather (ws too small) -------------
__global__ void __launch_bounds__(64, 1) ctc_direct_kernel(
        const float* __restrict__ logp, const int* __restrict__ targets,
        const int* __restrict__ input_lens, const int* __restrict__ target_lens,
        float* __restrict__ out) {
    const int b = blockIdx.x;
    const int lane = threadIdx.x;
    const int col = (lane <= 50) ? 4 * lane : 200;
    const int Tb = input_lens[b];
    const int tl = target_lens[b];

    int cc[4]; float mm[4], pm[4];
#pragma unroll
    for (int i = 0; i < 4; ++i) {
        const int l = col + i;
        const bool real = (lane <= 50) && (l < L);
        pm[i] = real ? 1.f : 0.f;
        cc[i] = real ? ((l & 1) ? targets[b * S + (l >> 1)] : 0) : 0;
        float mk = 0.f;
        if (real && (l & 1) && l >= 3) {
            const int s = (l - 1) >> 1;
            if (targets[b * S + s] != targets[b * S + s - 1]) mk = 1.f;
        }
        mm[i] = mk;
    }
    const float m1 = mm[1], m3 = mm[3];

    float a0 = 0.f, a1 = 0.f, a2 = 0.f, a3 = 0.f;
    {
        const float* rowp = logp + (size_t)b * C;
        const float p0 = pm[0] * exp2f((rowp[cc[0]] + OFF) * LOG2E);
        const float p1 = pm[1] * exp2f((rowp[cc[1]] + OFF) * LOG2E);
        if (lane == 0) { a0 = p0; a1 = p1; }
    }
    int esum = 0;

    for (int t = 1; t < Tb; ++t) {
        const float* rowp = logp + ((size_t)t * B + b) * C;
        const float p0 = pm[0] * exp2f((rowp[cc[0]] + OFF) * LOG2E);
        const float p1 = pm[1] * exp2f((rowp[cc[1]] + OFF) * LOG2E);
        const float p2 = pm[2] * exp2f((rowp[cc[2]] + OFF) * LOG2E);
        const float p3 = pm[3] * exp2f((rowp[cc[3]] + OFF) * LOG2E);
        const float am1 = dpp_shr1(a3);
        const float n0 = (a0 + am1) * p0;
        const float n1 = fmaf(am1, m1, a0 + a1) * p1;
        const float n2 = (a1 + a2) * p2;
        const float n3 = fmaf(a1, m3, a2 + a3) * p3;
        a0 = n0; a1 = n1; a2 = n2; a3 = n3;
        if ((t & 15) == 0) {
            const float mx = wave_max_nonneg(fmaxf(fmaxf(a0, a1), fmaxf(a2, a3)));
            const unsigned bits = __float_as_uint(mx);
            if (bits != 0u) {
                const int e = (int)((bits >> 23) & 0xFFu) - 127;
                const float sc = __uint_as_float((unsigned)(127 - e) << 23);
                a0 *= sc; a1 *= sc; a2 *= sc; a3 *= sc;
                esum += e;
            }
        }
    }

    const int e1 = 2 * tl, e2 = 2 * tl - 1;
    float contrib = 0.f;
    if (lane <= 50) {
        if (col + 0 == e1 || col + 0 == e2) contrib += a0;
        if (col + 1 == e1 || col + 1 == e2) contrib += a1;
        if (col + 2 == e1 || col + 2 == e2) contrib += a2;
        if (col + 3 == e1 || col + 3 == e2) contrib += a3;
    }
#pragma unroll
    for (int off = 32; off; off >>= 1) contrib += __shfl_xor(contrib, off);
    if (lane == 0) {
        const float logalpha = logf(contrib) + (float)esum * LN2 - OFF * (float)Tb;
        float loss = -logalpha;
        if (!(loss < 0.5e30f)) loss = 0.f;
        atomicAdd(out, loss);
    }
}

extern "C" void kernel_launch(void* const* d_in, const int* in_sizes, int n_in,
                              void* d_out, int out_size, void* d_ws, size_t ws_size,
                              hipStream_t stream) {
    (void)in_sizes; (void)n_in; (void)out_size;
    const float* logp = (const float*)d_in[0];
    const int* targets = (const int*)d_in[1];
    const int* input_lens = (const int*)d_in[2];
    const int* target_lens = (const int*)d_in[3];
    float* out = (float*)d_out;
    float* ws = (float*)d_ws;

    // One-time, capture-safe host queries: decide the coop path WITHOUT ever
    // issuing a launch that could fail during graph capture (round-5 lesson).
    static int s_coop = -1;
    if (s_coop < 0) {
        int nb = 0, ncu = 0, dev = 0, coopOk = 0;
        hipError_t e = hipGetDevice(&dev);
        if (e == hipSuccess)
            e = hipDeviceGetAttribute(&coopOk, hipDeviceAttributeCooperativeLaunch,
                                      dev);
        if (e == hipSuccess)
            e = hipDeviceGetAttribute(&ncu, hipDeviceAttributeMultiprocessorCount,
                                      dev);
        if (e == hipSuccess)
            e = hipOccupancyMaxActiveBlocksPerMultiprocessor(&nb, ctc_coop_kernel,
                                                             BTHR, 0);
        s_coop = (e == hipSuccess && coopOk && nb >= 1 &&
                  (long long)nb * ncu >= GBLK)
                     ? 1
                     : 0;
    }

    const size_t ws_needed = (DATA_WORDS + (size_t)B) * sizeof(float);
    if (ws_size >= ws_needed && s_coop == 1) {
        void* args[] = {(void*)&logp, (void*)&targets, (void*)&input_lens,
                        (void*)&target_lens, (void*)&ws, (void*)&out};
        const hipError_t err = hipLaunchCooperativeKernel(
            (const void*)ctc_coop_kernel, dim3(GBLK), dim3(BTHR), args, 0, stream);
        if (err == hipSuccess) return;
        s_coop = 0;  // never try again; fall through to the proven path
    }
    if (ws_size >= ws_needed) {
        hipMemsetAsync(d_out, 0, sizeof(float), stream);
        dim3 gA(T / 4, B);
        stage_kernel<<<gA, 256, 0, stream>>>(logp, targets, ws);
        ctc_kernel<<<B, 64, 0, stream>>>(ws, targets, input_lens, target_lens, out);
    } else {
        hipMemsetAsync(d_out, 0, sizeof(float), stream);
        ctc_direct_kernel<<<B, 64, 0, stream>>>(logp, targets, input_lens,
                                                target_lens, out);
    }
}

// Round 10
// 228.702 us; speedup vs baseline: 7.2015x; 1.0469x over previous
//
#include <hip/hip_runtime.h>

// CTC loss forward, sum over batch — two proven kernels, minimal serial chain.
//
// Round-9 lesson: cross-block spin/flag protocols are unsafe here (r3: L2
// storm 7x slowdown; r9: container hang under graph/rocprof replay).
// Cross-block deps must go through dispatch boundaries only.
//
// This round is strictly-subtractive from the 234.7/234.9 us builds:
//   Kernel A (stage): r0's PROVEN coalesced pattern — one block per (t,b),
//     full 4KB row float4 -> LDS -> gather ~102 cols -> exp2(+OFF) -> fp32
//     ws row (816B). Block (0,0) also zeroes out[0], deleting the separate
//     memset dispatch (stream order: stage completes before ctc starts).
//   Kernel B (ctc): r2's PROVEN recurrence — one wave per batch element,
//     __launch_bounds__(64,1) (512-VGPR budget -> PFD=32 float4 ring is
//     register-resident, no r8-style spill), DPP wave_shr:1 cross-lane,
//     exact pow2 rescale every 16 steps (esum carries the log scale).
// Decision round: if total stays ~235 with our chain at ~60us (vs r0's
// ~87us), the remaining time is harness-structural (poison fills + graph
// overhead) and the next verdict is ROOFLINE.

constexpr int T = 1000, B = 32, C = 1000, S = 100;
constexpr int L = 2 * S + 1;      // 201
constexpr int RS = 204;           // row stride (floats) = 816 B, 16B-aligned
constexpr int PFD = 32;           // prefetch ring depth (recurrence)
constexpr int RROWS = T + PFD;    // pad rows so ring prefetch stays in-bounds
constexpr float OFF = 7.0f;       // emission log-offset
constexpr float LOG2E = 1.4426950408889634f;
constexpr float LN2 = 0.6931471805599453f;

constexpr size_t DATA_WORDS = (size_t)B * RROWS * RS;  // ~26.9 MB of floats

// DPP wave_shr:1 — lane i reads lane i-1; lane 0 gets 0 (bound_ctrl).
__device__ __forceinline__ float dpp_shr1(float x) {
    return __int_as_float(
        __builtin_amdgcn_update_dpp(0, __float_as_int(x), 0x138, 0xF, 0xF, true));
}

// Wave-wide max of NONNEGATIVE values via gfx9 DPP ladder; result uniform.
__device__ __forceinline__ float wave_max_nonneg(float x) {
#define DPP_MAX(ctrl)                                                        \
    x = fmaxf(x, __int_as_float(__builtin_amdgcn_update_dpp(                 \
                     0, __float_as_int(x), (ctrl), 0xF, 0xF, true)))
    DPP_MAX(0x111);  // row_shr:1
    DPP_MAX(0x112);  // row_shr:2
    DPP_MAX(0x114);  // row_shr:4
    DPP_MAX(0x118);  // row_shr:8
    DPP_MAX(0x142);  // row_bcast15
    DPP_MAX(0x143);  // row_bcast31 -> lane63 holds wave max
#undef DPP_MAX
    return __int_as_float(__builtin_amdgcn_readlane(__float_as_int(x), 63));
}

// ---------------- Kernel A: coalesced stage (r0-proven pattern) ----------------
// grid (T, B), 256 threads. Full row -> LDS -> gather -> fp32 ws row.
__global__ void __launch_bounds__(256) stage_kernel(
        const float* __restrict__ logp, const int* __restrict__ targets,
        float* __restrict__ ws, float* __restrict__ out) {
    const int t = blockIdx.x;
    const int b = blockIdx.y;
    __shared__ float row[C];
    const float* src = logp + ((size_t)t * B + b) * C;
    const int tid = threadIdx.x;
    if (tid < C / 4) {
        ((float4*)row)[tid] = ((const float4*)src)[tid];
    }
    __syncthreads();
    if (t == 0 && b == 0 && tid == 0) out[0] = 0.f;  // folded memset
    if (tid < RS) {
        float p;
        if (tid < L) {
            const int c = (tid & 1) ? targets[b * S + (tid >> 1)] : 0;
            p = exp2f((row[c] + OFF) * LOG2E);
        } else {
            p = 0.0f;  // pad cols 201..203 -> keeps lane-50 dead-lane invariant
        }
        ws[((size_t)b * RROWS + t) * RS + tid] = p;
    }
}

// ---------------- Kernel B: recurrence (r2-proven) ----------------
__global__ void __launch_bounds__(64, 1) ctc_kernel(
        const float* __restrict__ ws, const int* __restrict__ targets,
        const int* __restrict__ input_lens, const int* __restrict__ target_lens,
        float* __restrict__ out) {
    const int b = blockIdx.x;
    const int lane = threadIdx.x;
    // lanes 0..50 own positions 4*lane..4*lane+3; lanes 51..63 dead (clamped)
    const int col = (lane <= 50) ? 4 * lane : 200;
    const int Tb = min(input_lens[b], T);
    const int tl = target_lens[b];
    const float* pw = ws + (size_t)b * RROWS * RS;

    // Skip masks: only odd positions (col+1, col+3) can skip.
    float m1 = 0.f, m3 = 0.f;
    if (lane <= 50) {
        const int l1 = col + 1;
        if (l1 >= 3 && l1 < L) {
            const int s = (l1 - 1) >> 1;
            if (targets[b * S + s] != targets[b * S + s - 1]) m1 = 1.f;
        }
        const int l3 = col + 3;
        if (l3 >= 3 && l3 < L) {
            const int s = (l3 - 1) >> 1;
            if (targets[b * S + s] != targets[b * S + s - 1]) m3 = 1.f;
        }
    }

    // init at t=0: alpha[0] = p(blank), alpha[1] = p(tgt0), rest 0
    float a0 = 0.f, a1 = 0.f, a2 = 0.f, a3 = 0.f;
    {
        const float4 q0 = *reinterpret_cast<const float4*>(pw + col);
        if (lane == 0) { a0 = q0.x; a1 = q0.y; }
    }
    int esum = 0;

    // Dead-lane invariant: lane 50's cols 201..203 staged 0 -> its a1..a3
    // stay 0; lanes 51+ start 0 and only ever receive lane 50's zero a3.
#define CTC_STEP(Q_)                                  \
    do {                                              \
        const float am1 = dpp_shr1(a3);               \
        const float s01 = a0 + a1;                    \
        const float s23 = a2 + a3;                    \
        const float n0 = (a0 + am1) * (Q_).x;         \
        const float n1 = fmaf(am1, m1, s01) * (Q_).y; \
        const float n2 = (a1 + a2) * (Q_).z;          \
        const float n3 = fmaf(a1, m3, s23) * (Q_).w;  \
        a0 = n0; a1 = n1; a2 = n2; a3 = n3;           \
    } while (0)

#define CTC_RESCALE()                                                          \
    do {                                                                       \
        const float mx = wave_max_nonneg(fmaxf(fmaxf(a0, a1), fmaxf(a2, a3))); \
        const unsigned bits = __float_as_uint(mx);                             \
        if (bits != 0u) {                                                      \
            const int e = (int)((bits >> 23) & 0xFFu) - 127;                   \
            const float sc = __uint_as_float((unsigned)(127 - e) << 23);       \
            a0 *= sc; a1 *= sc; a2 *= sc; a3 *= sc;                            \
            esum += e;                                                         \
        }                                                                      \
    } while (0)

    // prefetch ring: P[i] holds the emission row (float4) for step t+i
    float4 P[PFD];
    {
        const float* pf0 = pw + (size_t)RS + col;
#pragma unroll
        for (int i = 0; i < PFD; ++i)
            P[i] = *reinterpret_cast<const float4*>(pf0 + (size_t)i * RS);
    }
    const float* pf = pw + (size_t)(PFD + 1) * RS + col;  // next row to fetch

    int t = 1;
    while (t + PFD <= Tb) {
#pragma unroll
        for (int i = 0; i < PFD; ++i) {
            const float4 q = P[i];
            P[i] = *reinterpret_cast<const float4*>(pf);  // PFD steps ahead
            pf += RS;
            CTC_STEP(q);
            if (i == 15) CTC_RESCALE();  // 16-step rescale cadence
        }
        CTC_RESCALE();
        t += PFD;
    }
    // tail (< PFD steps)
    {
        const int rem = Tb - t;
#pragma unroll
        for (int i = 0; i < PFD; ++i) {
            if (i < rem) {
                const float4 q = P[i];
                CTC_STEP(q);
                if (i == 15) CTC_RESCALE();  // bound any unrescaled run
            }
        }
    }
#undef CTC_STEP
#undef CTC_RESCALE

    // final: sum alpha at positions 2*tl and 2*tl-1
    const int e1 = 2 * tl, e2 = 2 * tl - 1;
    float contrib = 0.f;
    if (lane <= 50) {
        if (col + 0 == e1 || col + 0 == e2) contrib += a0;
        if (col + 1 == e1 || col + 1 == e2) contrib += a1;
        if (col + 2 == e1 || col + 2 == e2) contrib += a2;
        if (col + 3 == e1 || col + 3 == e2) contrib += a3;
    }
#pragma unroll
    for (int off = 32; off; off >>= 1) contrib += __shfl_xor(contrib, off);

    if (lane == 0) {
        const float logalpha = logf(contrib) + (float)esum * LN2 - OFF * (float)Tb;
        float loss = -logalpha;
        if (!(loss < 0.5e30f)) loss = 0.f;  // zero_infinity (catches NaN/inf)
        atomicAdd(out, loss);
    }
}

// ------------- fallback: direct gather (ws too small) -------------
__global__ void __launch_bounds__(64, 1) ctc_direct_kernel(
        const float* __restrict__ logp, const int* __restrict__ targets,
        const int* __restrict__ input_lens, const int* __restrict__ target_lens,
        float* __restrict__ out) {
    const int b = blockIdx.x;
    const int lane = threadIdx.x;
    const int col = (lane <= 50) ? 4 * lane : 200;
    const int Tb = input_lens[b];
    const int tl = target_lens[b];

    int cc[4]; float mm[4], pm[4];
#pragma unroll
    for (int i = 0; i < 4; ++i) {
        const int l = col + i;
        const bool real = (lane <= 50) && (l < L);
        pm[i] = real ? 1.f : 0.f;
        cc[i] = real ? ((l & 1) ? targets[b * S + (l >> 1)] : 0) : 0;
        float mk = 0.f;
        if (real && (l & 1) && l >= 3) {
            const int s = (l - 1) >> 1;
            if (targets[b * S + s] != targets[b * S + s - 1]) mk = 1.f;
        }
        mm[i] = mk;
    }
    const float m1 = mm[1], m3 = mm[3];

    float a0 = 0.f, a1 = 0.f, a2 = 0.f, a3 = 0.f;
    {
        const float* rowp = logp + (size_t)b * C;
        const float p0 = pm[0] * exp2f((rowp[cc[0]] + OFF) * LOG2E);
        const float p1 = pm[1] * exp2f((rowp[cc[1]] + OFF) * LOG2E);
        if (lane == 0) { a0 = p0; a1 = p1; }
    }
    int esum = 0;

    for (int t = 1; t < Tb; ++t) {
        const float* rowp = logp + ((size_t)t * B + b) * C;
        const float p0 = pm[0] * exp2f((rowp[cc[0]] + OFF) * LOG2E);
        const float p1 = pm[1] * exp2f((rowp[cc[1]] + OFF) * LOG2E);
        const float p2 = pm[2] * exp2f((rowp[cc[2]] + OFF) * LOG2E);
        const float p3 = pm[3] * exp2f((rowp[cc[3]] + OFF) * LOG2E);
        const float am1 = dpp_shr1(a3);
        const float n0 = (a0 + am1) * p0;
        const float n1 = fmaf(am1, m1, a0 + a1) * p1;
        const float n2 = (a1 + a2) * p2;
        const float n3 = fmaf(a1, m3, a2 + a3) * p3;
        a0 = n0; a1 = n1; a2 = n2; a3 = n3;
        if ((t & 15) == 0) {
            const float mx = wave_max_nonneg(fmaxf(fmaxf(a0, a1), fmaxf(a2, a3)));
            const unsigned bits = __float_as_uint(mx);
            if (bits != 0u) {
                const int e = (int)((bits >> 23) & 0xFFu) - 127;
                const float sc = __uint_as_float((unsigned)(127 - e) << 23);
                a0 *= sc; a1 *= sc; a2 *= sc; a3 *= sc;
                esum += e;
            }
        }
    }

    const int e1 = 2 * tl, e2 = 2 * tl - 1;
    float contrib = 0.f;
    if (lane <= 50) {
        if (col + 0 == e1 || col + 0 == e2) contrib += a0;
        if (col + 1 == e1 || col + 1 == e2) contrib += a1;
        if (col + 2 == e1 || col + 2 == e2) contrib += a2;
        if (col + 3 == e1 || col + 3 == e2) contrib += a3;
    }
#pragma unroll
    for (int off = 32; off; off >>= 1) contrib += __shfl_xor(contrib, off);
    if (lane == 0) {
        const float logalpha = logf(contrib) + (float)esum * LN2 - OFF * (float)Tb;
        float loss = -logalpha;
        if (!(loss < 0.5e30f)) loss = 0.f;
        atomicAdd(out, loss);
    }
}

extern "C" void kernel_launch(void* const* d_in, const int* in_sizes, int n_in,
                              void* d_out, int out_size, void* d_ws, size_t ws_size,
                              hipStream_t stream) {
    (void)in_sizes; (void)n_in; (void)out_size;
    const float* logp = (const float*)d_in[0];
    const int* targets = (const int*)d_in[1];
    const int* input_lens = (const int*)d_in[2];
    const int* target_lens = (const int*)d_in[3];
    float* out = (float*)d_out;
    float* ws = (float*)d_ws;

    const size_t ws_needed = DATA_WORDS * sizeof(float);
    if (ws_size >= ws_needed) {
        dim3 gA(T, B);
        stage_kernel<<<gA, 256, 0, stream>>>(logp, targets, ws, out);
        ctc_kernel<<<B, 64, 0, stream>>>(ws, targets, input_lens, target_lens, out);
    } else {
        hipMemsetAsync(d_out, 0, sizeof(float), stream);
        ctc_direct_kernel<<<B, 64, 0, stream>>>(logp, targets, input_lens,
                                                target_lens, out);
    }
}